// Round 3
// baseline (2395.866 us; speedup 1.0000x reference)
//
#include <hip/hip_runtime.h>
#include <math.h>

#define N_SP 65536   // h*w
#define IMG  256

// ---------------------------------------------------------------------------
// GEMM: C[row0+r, n] = sum_{c<192} W[(wrow0+row0+r)*192 + c] * X[c*N_SP + n]
// Block: 256 threads -> tile of 192 rows x 64 columns. Thread = 12 rows x 4 cols.
// Used for K1 (qkv 1x1 conv, per batch) and K4 (fused M @ v, in-place on d_out).
// In-place safety (K4): a block reads only columns [n0,n0+64) of X and writes the
// same columns of C; __syncthreads() (vmcnt(0) drain) after the last k-step orders
// all reads before any write within the block; blocks touch disjoint columns.
// NOTE: X/C deliberately NOT __restrict__ (K4 aliases them).
// ---------------------------------------------------------------------------
__global__ __launch_bounds__(256) void gemm192(
    const float* __restrict__ W, const float* X, float* C,
    int wrow0, long long wBS, long long xBS, long long cBS)
{
    __shared__ float Wld[192][33];   // +1 pad: conflict-free
    const int t   = threadIdx.x;
    const int cq  = t & 15;          // column quad (4 cols each)
    const int rg  = t >> 4;          // row group (12 rows each)
    const int rbase = rg * 12;
    const long long n0 = (long long)blockIdx.x * 64;
    const int row0 = blockIdx.y * 192;
    const int b    = blockIdx.z;
    const float* Wb = W + (long long)b * wBS + (long long)(wrow0 + row0) * 192;
    const float* Xb = X + (long long)b * xBS;

    float acc[12][4];
    #pragma unroll
    for (int r = 0; r < 12; ++r) { acc[r][0]=0.f; acc[r][1]=0.f; acc[r][2]=0.f; acc[r][3]=0.f; }

    for (int c0 = 0; c0 < 192; c0 += 32) {
        #pragma unroll
        for (int i = 0; i < 24; ++i) {              // 192*32 elements / 256 threads
            int id = t + i * 256;
            int rr = id >> 5, cc = id & 31;
            Wld[rr][cc] = Wb[rr * 192 + c0 + cc];
        }
        __syncthreads();
        #pragma unroll 8
        for (int cc = 0; cc < 32; ++cc) {
            const float4 xv = *(const float4*)(Xb + (long long)(c0 + cc) * N_SP + n0 + cq * 4);
            #pragma unroll
            for (int r = 0; r < 12; ++r) {
                float wv = Wld[rbase + r][cc];      // 16-lane broadcast
                acc[r][0] = fmaf(wv, xv.x, acc[r][0]);
                acc[r][1] = fmaf(wv, xv.y, acc[r][1]);
                acc[r][2] = fmaf(wv, xv.z, acc[r][2]);
                acc[r][3] = fmaf(wv, xv.w, acc[r][3]);
            }
        }
        __syncthreads();
    }
    float* Cb = C + (long long)b * cBS + n0 + cq * 4;
    #pragma unroll
    for (int r = 0; r < 12; ++r) {
        float4 o; o.x = acc[r][0]; o.y = acc[r][1]; o.z = acc[r][2]; o.w = acc[r][3];
        *(float4*)(Cb + (long long)(row0 + rbase + r) * N_SP) = o;
    }
}

// ---------------------------------------------------------------------------
// K2qk: depthwise 3x3 on q,k channels of one head over a 64x4 pixel tile, then
// reduce straight to G = q k^T partials + sum-of-squares (atomics). Post-DW q,k
// never touch HBM. buf channels: q at [h*32+c], k at [192+h*32+c].
// kT second dim MUST be >= 32 (round-2 bug: [30] overflowed into neighbor rows).
// ---------------------------------------------------------------------------
__global__ __launch_bounds__(256) void dw_qk(
    const float* __restrict__ buf, const float* __restrict__ dww,
    float* __restrict__ G, float* __restrict__ Sq, float* __restrict__ Sk, int b)
{
    __shared__ float qT[256][34];
    __shared__ float kT[256][34];
    const int t = threadIdx.x;
    const int tile = blockIdx.x, h = blockIdx.y;
    const int ty0 = (tile >> 2) * 4, tx0 = (tile & 3) * 64;
    const int py = t >> 6, px = t & 63;
    const int gy = ty0 + py, gx = tx0 + px;

    int  yo[3], xo[3]; bool vy[3], vx[3];
    #pragma unroll
    for (int d = 0; d < 3; ++d) {
        int yy = gy + d - 1; vy[d] = (yy >= 0 && yy < IMG); yo[d] = yy * IMG;
        int xx = gx + d - 1; vx[d] = (xx >= 0 && xx < IMG); xo[d] = xx;
    }

    for (int ch = 0; ch < 64; ++ch) {
        const int gch = (ch < 32) ? (h * 32 + ch) : (192 + h * 32 + (ch - 32));
        const float* base = buf + ((long long)gch << 16);
        const float* wp = dww + gch * 9;
        float s = 0.f;
        #pragma unroll
        for (int dy = 0; dy < 3; ++dy) {
            if (vy[dy]) {
                #pragma unroll
                for (int dx = 0; dx < 3; ++dx) {
                    if (vx[dx]) s = fmaf(wp[dy * 3 + dx], base[yo[dy] + xo[dx]], s);
                }
            }
        }
        if (ch < 32) qT[t][ch] = s; else kT[t][ch - 32] = s;
    }
    __syncthreads();

    // Phase 2: wave w covers pixels [64w,64w+64); lane covers a 4x4 (c,d) tile.
    const int w = t >> 6, l = t & 63;
    const int cqd = l >> 3, dqd = l & 7;
    float acc[4][4];
    #pragma unroll
    for (int i = 0; i < 4; ++i) { acc[i][0]=0.f; acc[i][1]=0.f; acc[i][2]=0.f; acc[i][3]=0.f; }
    float sq[4] = {0.f,0.f,0.f,0.f}, sk[4] = {0.f,0.f,0.f,0.f};
    const int nb = w * 64;
    for (int n = nb; n < nb + 64; ++n) {
        float2 qa0 = *(const float2*)&qT[n][cqd * 4];
        float2 qa1 = *(const float2*)&qT[n][cqd * 4 + 2];
        float2 kb0 = *(const float2*)&kT[n][dqd * 4];
        float2 kb1 = *(const float2*)&kT[n][dqd * 4 + 2];
        float qa[4] = {qa0.x, qa0.y, qa1.x, qa1.y};
        float kb[4] = {kb0.x, kb0.y, kb1.x, kb1.y};
        #pragma unroll
        for (int i = 0; i < 4; ++i) {
            #pragma unroll
            for (int j = 0; j < 4; ++j) acc[i][j] = fmaf(qa[i], kb[j], acc[i][j]);
        }
        if (dqd == 0) {
            #pragma unroll
            for (int i = 0; i < 4; ++i) sq[i] = fmaf(qa[i], qa[i], sq[i]);
        }
        if (cqd == 0) {
            #pragma unroll
            for (int j = 0; j < 4; ++j) sk[j] = fmaf(kb[j], kb[j], sk[j]);
        }
    }
    float* Gb = G + (long long)((b * 6 + h) * 32) * 32;
    #pragma unroll
    for (int i = 0; i < 4; ++i) {
        #pragma unroll
        for (int j = 0; j < 4; ++j)
            atomicAdd(&Gb[(cqd * 4 + i) * 32 + dqd * 4 + j], acc[i][j]);
    }
    if (dqd == 0) {
        #pragma unroll
        for (int i = 0; i < 4; ++i) atomicAdd(&Sq[(b * 6 + h) * 32 + cqd * 4 + i], sq[i]);
    }
    if (cqd == 0) {
        #pragma unroll
        for (int j = 0; j < 4; ++j) atomicAdd(&Sk[(b * 6 + h) * 32 + dqd * 4 + j], sk[j]);
    }
}

// ---------------------------------------------------------------------------
// K2v: depthwise 3x3 on 192 v channels. vsrc = staged pre-DW v (channel c at
// vsrc + c*N_SP); weights at dwwv + c*9 (caller passes dww+384*9); writes vout.
// ---------------------------------------------------------------------------
__global__ __launch_bounds__(256) void dw_v(
    const float* __restrict__ vsrc, const float* __restrict__ dwwv, float* __restrict__ vout)
{
    const int t = threadIdx.x;
    const int tile = blockIdx.x, cg = blockIdx.y;
    const int ty0 = (tile >> 2) * 4, tx0 = (tile & 3) * 64;
    const int py = t >> 6, px = t & 63;
    const int gy = ty0 + py, gx = tx0 + px;

    int  yo[3], xo[3]; bool vy[3], vx[3];
    #pragma unroll
    for (int d = 0; d < 3; ++d) {
        int yy = gy + d - 1; vy[d] = (yy >= 0 && yy < IMG); yo[d] = yy * IMG;
        int xx = gx + d - 1; vx[d] = (xx >= 0 && xx < IMG); xo[d] = xx;
    }
    #pragma unroll
    for (int i = 0; i < 4; ++i) {
        const int c = cg * 4 + i;
        const float* base = vsrc + ((long long)c << 16);
        const float* wp = dwwv + c * 9;
        float s = 0.f;
        #pragma unroll
        for (int dy = 0; dy < 3; ++dy) {
            if (vy[dy]) {
                #pragma unroll
                for (int dx = 0; dx < 3; ++dx) {
                    if (vx[dx]) s = fmaf(wp[dy * 3 + dx], base[yo[dy] + xo[dx]], s);
                }
            }
        }
        vout[((long long)c << 16) + gy * IMG + gx] = s;
    }
}

// ---------------------------------------------------------------------------
// K3a: per (b,head): attn = G/(nq nk) * T; exact 16th-largest threshold per
// row; masked softmax; fold attn1. One thread per row c.
// ---------------------------------------------------------------------------
__global__ void attn_small(const float* __restrict__ G, const float* __restrict__ Sq,
                           const float* __restrict__ Sk, const float* __restrict__ temp,
                           const float* __restrict__ attn1, float* __restrict__ A)
{
    const int h = blockIdx.x, b = blockIdx.y, c = threadIdx.x;
    const int bh = b * 6 + h;
    const float* g = G + ((long long)bh * 32 + c) * 32;
    const float nq = fmaxf(sqrtf(Sq[bh * 32 + c]), 1e-12f);
    const float T  = temp[h];
    const float a1 = attn1[0];

    float a[32];
    #pragma unroll
    for (int d = 0; d < 32; ++d) {
        float nk = fmaxf(sqrtf(Sk[bh * 32 + d]), 1e-12f);
        a[d] = g[d] / (nq * nk) * T;
    }
    unsigned mask = 0u;
    float m = 0.f, kth = 0.f;
    for (int it = 0; it < 16; ++it) {
        float best = -3.4e38f; int bi = 0;
        #pragma unroll
        for (int d = 0; d < 32; ++d) {
            bool avail = ((mask >> d) & 1u) == 0u;
            if (avail && a[d] > best) { best = a[d]; bi = d; }
        }
        mask |= (1u << bi);
        if (it == 0) m = best;
        kth = best;
    }
    float denom = 0.f;
    #pragma unroll
    for (int d = 0; d < 32; ++d) if (a[d] >= kth) denom += expf(a[d] - m);
    const float inv = a1 / denom;
    float* Ar = A + ((long long)bh * 32 + c) * 32;
    #pragma unroll
    for (int d = 0; d < 32; ++d) Ar[d] = (a[d] >= kth) ? expf(a[d] - m) * inv : 0.f;
}

// ---------------------------------------------------------------------------
// K3b: M[b][o][hd*32+d] = sum_cq proj_w[o][hd*32+cq] * A[b][hd][cq][d]
// ---------------------------------------------------------------------------
__global__ void make_m(const float* __restrict__ proj_w, const float* __restrict__ A,
                       float* __restrict__ M)
{
    const int o = blockIdx.x, b = blockIdx.y, j = threadIdx.x;
    const int hd = j >> 5, d = j & 31;
    const float* pw = proj_w + o * 192 + hd * 32;
    const float* Ah = A + ((long long)(b * 6 + hd) * 32) * 32 + d;
    float s = 0.f;
    #pragma unroll
    for (int cq = 0; cq < 32; ++cq) s = fmaf(pw[cq], Ah[cq * 32], s);
    M[((long long)(b * 192 + o)) * 192 + j] = s;
}

// ---------------------------------------------------------------------------
extern "C" void kernel_launch(void* const* d_in, const int* in_sizes, int n_in,
                              void* d_out, int out_size, void* d_ws, size_t ws_size,
                              hipStream_t stream)
{
    const float* x      = (const float*)d_in[0];
    const float* qkv_w  = (const float*)d_in[1];
    const float* dww    = (const float*)d_in[2];
    const float* proj_w = (const float*)d_in[3];
    const float* temp   = (const float*)d_in[4];
    const float* attn1  = (const float*)d_in[5];
    float* out = (float*)d_out;
    float* wsf = (float*)d_ws;

    // ws layout (floats): tiny tensors FIRST (396 KB), big staging buffer after.
    float* G   = wsf;                 // 12,288
    float* Sq  = G + 12288;           // 384
    float* Sk  = Sq + 384;            // 384
    float* A   = Sk + 384;            // 12,288
    float* M   = A + 12288;           // 73,728
    float* buf = M + 73728;           // staging (151 MB path A / 101 MB path B)

    const long long xBatch = 192LL * N_SP;   // x / out per-batch stride
    const bool bigWs = (ws_size >= (size_t)(99072 + 576LL * N_SP) * sizeof(float));

    hipMemsetAsync(G, 0, (size_t)(12288 + 768) * sizeof(float), stream);

    for (int b = 0; b < 2; ++b) {
        const float* xb = x + (long long)b * xBatch;
        float* outb = out + (long long)b * xBatch;
        if (bigWs) {
            // K1: all 576 qkv rows into buf
            gemm192<<<dim3(1024, 3, 1), 256, 0, stream>>>(qkv_w, xb, buf, 0, 0, 0, 0);
            dw_qk<<<dim3(256, 6, 1), 256, 0, stream>>>(buf, dww, G, Sq, Sk, b);
            dw_v<<<dim3(256, 48, 1), 256, 0, stream>>>(buf + 384LL * N_SP, dww + 384 * 9, outb);
        } else {
            // K1 split: q,k rows (0..383) first; then v rows (384..575) reuse buf ch 0..191
            gemm192<<<dim3(1024, 2, 1), 256, 0, stream>>>(qkv_w, xb, buf, 0, 0, 0, 0);
            dw_qk<<<dim3(256, 6, 1), 256, 0, stream>>>(buf, dww, G, Sq, Sk, b);
            gemm192<<<dim3(1024, 1, 1), 256, 0, stream>>>(qkv_w, xb, buf, 384, 0, 0, 0);
            dw_v<<<dim3(256, 48, 1), 256, 0, stream>>>(buf, dww + 384 * 9, outb);
        }
    }

    attn_small<<<dim3(6, 2), 32, 0, stream>>>(G, Sq, Sk, temp, attn1, A);
    make_m<<<dim3(192, 2), 192, 0, stream>>>(proj_w, A, M);

    // K4: out = M @ v, in-place on d_out
    gemm192<<<dim3(1024, 1, 2), 256, 0, stream>>>(
        M, out, out, 0, 192LL * 192, xBatch, xBatch);
}

// Round 4
// 1961.039 us; speedup vs baseline: 1.2217x; 1.2217x over previous
//
#include <hip/hip_runtime.h>
#include <math.h>

#define N_SP 65536   // h*w
#define IMG  256

// ---------------------------------------------------------------------------
// GEMM: C[row0+r, n] = sum_{c<192} W[(wrow0+row0+r)*192 + c] * X[c*N_SP + n]
// Block: 256 threads -> tile of 192 rows x 64 columns. Thread = 12 rows x 4 cols.
// Used for K1 (qkv 1x1 conv, per batch) and K4 (fused M @ v, in-place on d_out).
// In-place safety (K4): a block reads only columns [n0,n0+64) of X and writes the
// same columns of C; __syncthreads() after the last k-step orders all reads before
// any write within the block; blocks touch disjoint columns.
// NOTE: X/C deliberately NOT __restrict__ (K4 aliases them).
// ---------------------------------------------------------------------------
__global__ __launch_bounds__(256) void gemm192(
    const float* __restrict__ W, const float* X, float* C,
    int wrow0, long long wBS, long long xBS, long long cBS)
{
    __shared__ float Wld[192][33];   // +1 pad: conflict-free
    const int t   = threadIdx.x;
    const int cq  = t & 15;          // column quad (4 cols each)
    const int rg  = t >> 4;          // row group (12 rows each)
    const int rbase = rg * 12;
    const long long n0 = (long long)blockIdx.x * 64;
    const int row0 = blockIdx.y * 192;
    const int b    = blockIdx.z;
    const float* Wb = W + (long long)b * wBS + (long long)(wrow0 + row0) * 192;
    const float* Xb = X + (long long)b * xBS;

    float acc[12][4];
    #pragma unroll
    for (int r = 0; r < 12; ++r) { acc[r][0]=0.f; acc[r][1]=0.f; acc[r][2]=0.f; acc[r][3]=0.f; }

    for (int c0 = 0; c0 < 192; c0 += 32) {
        #pragma unroll
        for (int i = 0; i < 24; ++i) {              // 192*32 elements / 256 threads
            int id = t + i * 256;
            int rr = id >> 5, cc = id & 31;
            Wld[rr][cc] = Wb[rr * 192 + c0 + cc];
        }
        __syncthreads();
        #pragma unroll 8
        for (int cc = 0; cc < 32; ++cc) {
            const float4 xv = *(const float4*)(Xb + (long long)(c0 + cc) * N_SP + n0 + cq * 4);
            #pragma unroll
            for (int r = 0; r < 12; ++r) {
                float wv = Wld[rbase + r][cc];      // 16-lane broadcast
                acc[r][0] = fmaf(wv, xv.x, acc[r][0]);
                acc[r][1] = fmaf(wv, xv.y, acc[r][1]);
                acc[r][2] = fmaf(wv, xv.z, acc[r][2]);
                acc[r][3] = fmaf(wv, xv.w, acc[r][3]);
            }
        }
        __syncthreads();
    }
    float* Cb = C + (long long)b * cBS + n0 + cq * 4;
    #pragma unroll
    for (int r = 0; r < 12; ++r) {
        float4 o; o.x = acc[r][0]; o.y = acc[r][1]; o.z = acc[r][2]; o.w = acc[r][3];
        *(float4*)(Cb + (long long)(row0 + rbase + r) * N_SP) = o;
    }
}

// ---------------------------------------------------------------------------
// K2qk: depthwise 3x3 on q,k channels of one head over a 64x4 pixel tile, then
// reduce to a per-block 32x32 G partial + Sq/Sk partials, written NON-ATOMICALLY
// to Gpart[h][tile][1088] ([1024 G][32 Sq][32 Sk]). Round-3 lesson: 6.3M global
// atomicAdds to 4KB of G serialized at L2 -> 710us. Now zero global atomics.
// ---------------------------------------------------------------------------
__global__ __launch_bounds__(256) void dw_qk(
    const float* __restrict__ buf, const float* __restrict__ dww,
    float* __restrict__ Gpart)
{
    __shared__ float qT[256][34];
    __shared__ float kT[256][34];
    const int t = threadIdx.x;
    const int tile = blockIdx.x, h = blockIdx.y;
    const int ty0 = (tile >> 2) * 4, tx0 = (tile & 3) * 64;
    const int py = t >> 6, px = t & 63;
    const int gy = ty0 + py, gx = tx0 + px;

    int  yo[3], xo[3]; bool vy[3], vx[3];
    #pragma unroll
    for (int d = 0; d < 3; ++d) {
        int yy = gy + d - 1; vy[d] = (yy >= 0 && yy < IMG); yo[d] = yy * IMG;
        int xx = gx + d - 1; vx[d] = (xx >= 0 && xx < IMG); xo[d] = xx;
    }

    for (int ch = 0; ch < 64; ++ch) {
        const int gch = (ch < 32) ? (h * 32 + ch) : (192 + h * 32 + (ch - 32));
        const float* base = buf + ((long long)gch << 16);
        const float* wp = dww + gch * 9;
        float s = 0.f;
        #pragma unroll
        for (int dy = 0; dy < 3; ++dy) {
            if (vy[dy]) {
                #pragma unroll
                for (int dx = 0; dx < 3; ++dx) {
                    if (vx[dx]) s = fmaf(wp[dy * 3 + dx], base[yo[dy] + xo[dx]], s);
                }
            }
        }
        if (ch < 32) qT[t][ch] = s; else kT[t][ch - 32] = s;
    }
    __syncthreads();

    // Phase 2: wave w covers pixels [64w,64w+64); lane covers a 4x4 (c,d) tile.
    const int w = t >> 6, l = t & 63;
    const int cqd = l >> 3, dqd = l & 7;
    float acc[4][4];
    #pragma unroll
    for (int i = 0; i < 4; ++i) { acc[i][0]=0.f; acc[i][1]=0.f; acc[i][2]=0.f; acc[i][3]=0.f; }
    float sq[4] = {0.f,0.f,0.f,0.f}, sk[4] = {0.f,0.f,0.f,0.f};
    const int nb = w * 64;
    for (int n = nb; n < nb + 64; ++n) {
        float2 qa0 = *(const float2*)&qT[n][cqd * 4];
        float2 qa1 = *(const float2*)&qT[n][cqd * 4 + 2];
        float2 kb0 = *(const float2*)&kT[n][dqd * 4];
        float2 kb1 = *(const float2*)&kT[n][dqd * 4 + 2];
        float qa[4] = {qa0.x, qa0.y, qa1.x, qa1.y};
        float kb[4] = {kb0.x, kb0.y, kb1.x, kb1.y};
        #pragma unroll
        for (int i = 0; i < 4; ++i) {
            #pragma unroll
            for (int j = 0; j < 4; ++j) acc[i][j] = fmaf(qa[i], kb[j], acc[i][j]);
        }
        if (dqd == 0) {
            #pragma unroll
            for (int i = 0; i < 4; ++i) sq[i] = fmaf(qa[i], qa[i], sq[i]);
        }
        if (cqd == 0) {
            #pragma unroll
            for (int j = 0; j < 4; ++j) sk[j] = fmaf(kb[j], kb[j], sk[j]);
        }
    }
    __syncthreads();                 // all phase-2 LDS reads done before reuse

    // Phase 3: cross-wave LDS reduction, one non-atomic partial write per block.
    float* red  = &qT[0][0];         // [4][1024] G partials per wave
    float* red2 = &kT[0][0];         // [4][32] Sq then [4][32] Sk at +128
    #pragma unroll
    for (int i = 0; i < 4; ++i) {
        #pragma unroll
        for (int j = 0; j < 4; ++j)
            red[w * 1024 + (cqd * 4 + i) * 32 + dqd * 4 + j] = acc[i][j];
    }
    if (dqd == 0) {
        #pragma unroll
        for (int i = 0; i < 4; ++i) red2[w * 32 + cqd * 4 + i] = sq[i];
    }
    if (cqd == 0) {
        #pragma unroll
        for (int j = 0; j < 4; ++j) red2[128 + w * 32 + dqd * 4 + j] = sk[j];
    }
    __syncthreads();

    float* Gp = Gpart + (long long)(h * 256 + tile) * 1088;
    #pragma unroll
    for (int i = 0; i < 4; ++i) {
        int slot = t + i * 256;
        Gp[slot] = red[slot] + red[1024 + slot] + red[2048 + slot] + red[3072 + slot];
    }
    if (t < 32) {
        Gp[1024 + t] = red2[t] + red2[32 + t] + red2[64 + t] + red2[96 + t];
    } else if (t < 64) {
        int c = t - 32;
        Gp[1056 + c] = red2[128 + c] + red2[160 + c] + red2[192 + c] + red2[224 + c];
    }
}

// ---------------------------------------------------------------------------
// reduce_g: sum 256 tile-partials per head -> G, Sq, Sk (non-atomic, exact).
// ---------------------------------------------------------------------------
__global__ void reduce_g(const float* __restrict__ Gpart, float* __restrict__ G,
                         float* __restrict__ Sq, float* __restrict__ Sk, int bh0)
{
    const int h = blockIdx.x, t = threadIdx.x;
    const float* Gp = Gpart + (long long)h * 256 * 1088;
    const int bh = bh0 + h;
    #pragma unroll
    for (int i = 0; i < 5; ++i) {
        int slot = t + i * 256;
        if (slot >= 1088) break;
        float s = 0.f;
        for (int tl = 0; tl < 256; ++tl) s += Gp[(long long)tl * 1088 + slot];
        if (slot < 1024)      G[(long long)bh * 1024 + slot] = s;
        else if (slot < 1056) Sq[bh * 32 + (slot - 1024)] = s;
        else                  Sk[bh * 32 + (slot - 1056)] = s;
    }
}

// ---------------------------------------------------------------------------
// K2v: depthwise 3x3 on 192 v channels. vsrc = staged pre-DW v (channel c at
// vsrc + c*N_SP); weights at dwwv + c*9 (caller passes dww+384*9); writes vout.
// ---------------------------------------------------------------------------
__global__ __launch_bounds__(256) void dw_v(
    const float* __restrict__ vsrc, const float* __restrict__ dwwv, float* __restrict__ vout)
{
    const int t = threadIdx.x;
    const int tile = blockIdx.x, cg = blockIdx.y;
    const int ty0 = (tile >> 2) * 4, tx0 = (tile & 3) * 64;
    const int py = t >> 6, px = t & 63;
    const int gy = ty0 + py, gx = tx0 + px;

    int  yo[3], xo[3]; bool vy[3], vx[3];
    #pragma unroll
    for (int d = 0; d < 3; ++d) {
        int yy = gy + d - 1; vy[d] = (yy >= 0 && yy < IMG); yo[d] = yy * IMG;
        int xx = gx + d - 1; vx[d] = (xx >= 0 && xx < IMG); xo[d] = xx;
    }
    #pragma unroll
    for (int i = 0; i < 4; ++i) {
        const int c = cg * 4 + i;
        const float* base = vsrc + ((long long)c << 16);
        const float* wp = dwwv + c * 9;
        float s = 0.f;
        #pragma unroll
        for (int dy = 0; dy < 3; ++dy) {
            if (vy[dy]) {
                #pragma unroll
                for (int dx = 0; dx < 3; ++dx) {
                    if (vx[dx]) s = fmaf(wp[dy * 3 + dx], base[yo[dy] + xo[dx]], s);
                }
            }
        }
        vout[((long long)c << 16) + gy * IMG + gx] = s;
    }
}

// ---------------------------------------------------------------------------
// K3a: per (b,head): attn = G/(nq nk) * T; exact 16th-largest threshold per
// row; masked softmax; fold attn1. One thread per row c.
// ---------------------------------------------------------------------------
__global__ void attn_small(const float* __restrict__ G, const float* __restrict__ Sq,
                           const float* __restrict__ Sk, const float* __restrict__ temp,
                           const float* __restrict__ attn1, float* __restrict__ A)
{
    const int h = blockIdx.x, b = blockIdx.y, c = threadIdx.x;
    const int bh = b * 6 + h;
    const float* g = G + ((long long)bh * 32 + c) * 32;
    const float nq = fmaxf(sqrtf(Sq[bh * 32 + c]), 1e-12f);
    const float T  = temp[h];
    const float a1 = attn1[0];

    float a[32];
    #pragma unroll
    for (int d = 0; d < 32; ++d) {
        float nk = fmaxf(sqrtf(Sk[bh * 32 + d]), 1e-12f);
        a[d] = g[d] / (nq * nk) * T;
    }
    unsigned mask = 0u;
    float m = 0.f, kth = 0.f;
    for (int it = 0; it < 16; ++it) {
        float best = -3.4e38f; int bi = 0;
        #pragma unroll
        for (int d = 0; d < 32; ++d) {
            bool avail = ((mask >> d) & 1u) == 0u;
            if (avail && a[d] > best) { best = a[d]; bi = d; }
        }
        mask |= (1u << bi);
        if (it == 0) m = best;
        kth = best;
    }
    float denom = 0.f;
    #pragma unroll
    for (int d = 0; d < 32; ++d) if (a[d] >= kth) denom += expf(a[d] - m);
    const float inv = a1 / denom;
    float* Ar = A + ((long long)bh * 32 + c) * 32;
    #pragma unroll
    for (int d = 0; d < 32; ++d) Ar[d] = (a[d] >= kth) ? expf(a[d] - m) * inv : 0.f;
}

// ---------------------------------------------------------------------------
// K3b: M[b][o][hd*32+d] = sum_cq proj_w[o][hd*32+cq] * A[b][hd][cq][d]
// ---------------------------------------------------------------------------
__global__ void make_m(const float* __restrict__ proj_w, const float* __restrict__ A,
                       float* __restrict__ M)
{
    const int o = blockIdx.x, b = blockIdx.y, j = threadIdx.x;
    const int hd = j >> 5, d = j & 31;
    const float* pw = proj_w + o * 192 + hd * 32;
    const float* Ah = A + ((long long)(b * 6 + hd) * 32) * 32 + d;
    float s = 0.f;
    #pragma unroll
    for (int cq = 0; cq < 32; ++cq) s = fmaf(pw[cq], Ah[cq * 32], s);
    M[((long long)(b * 192 + o)) * 192 + j] = s;
}

// ---------------------------------------------------------------------------
extern "C" void kernel_launch(void* const* d_in, const int* in_sizes, int n_in,
                              void* d_out, int out_size, void* d_ws, size_t ws_size,
                              hipStream_t stream)
{
    const float* x      = (const float*)d_in[0];
    const float* qkv_w  = (const float*)d_in[1];
    const float* dww    = (const float*)d_in[2];
    const float* proj_w = (const float*)d_in[3];
    const float* temp   = (const float*)d_in[4];
    const float* attn1  = (const float*)d_in[5];
    float* out = (float*)d_out;
    float* wsf = (float*)d_ws;

    // ws layout (floats): tiny tensors FIRST (396 KB), big staging buffer after.
    float* G   = wsf;                 // 12,288
    float* Sq  = G + 12288;           // 384
    float* Sk  = Sq + 384;            // 384
    float* A   = Sk + 384;            // 12,288
    float* M   = A + 12288;           // 73,728
    float* buf = M + 73728;           // staging (151 MB path A / 101 MB path B)

    const long long xBatch = 192LL * N_SP;   // x / out per-batch stride
    const bool bigWs = (ws_size >= (size_t)(99072 + 576LL * N_SP) * sizeof(float));

    for (int b = 0; b < 2; ++b) {
        const float* xb = x + (long long)b * xBatch;
        float* outb = out + (long long)b * xBatch;
        // Gpart scratch lives in d_out batch-b region (6x256x1088 = 6.7MB << 50MB);
        // consumed by reduce_g BEFORE dw_v overwrites the region (stream-ordered).
        float* Gpart = outb;
        if (bigWs) {
            gemm192<<<dim3(1024, 3, 1), 256, 0, stream>>>(qkv_w, xb, buf, 0, 0, 0, 0);
            dw_qk<<<dim3(256, 6, 1), 256, 0, stream>>>(buf, dww, Gpart);
            reduce_g<<<dim3(6, 1), 256, 0, stream>>>(Gpart, G, Sq, Sk, b * 6);
            dw_v<<<dim3(256, 48, 1), 256, 0, stream>>>(buf + 384LL * N_SP, dww + 384 * 9, outb);
        } else {
            gemm192<<<dim3(1024, 2, 1), 256, 0, stream>>>(qkv_w, xb, buf, 0, 0, 0, 0);
            dw_qk<<<dim3(256, 6, 1), 256, 0, stream>>>(buf, dww, Gpart);
            reduce_g<<<dim3(6, 1), 256, 0, stream>>>(Gpart, G, Sq, Sk, b * 6);
            gemm192<<<dim3(1024, 1, 1), 256, 0, stream>>>(qkv_w, xb, buf, 384, 0, 0, 0);
            dw_v<<<dim3(256, 48, 1), 256, 0, stream>>>(buf, dww + 384 * 9, outb);
        }
    }

    attn_small<<<dim3(6, 2), 32, 0, stream>>>(G, Sq, Sk, temp, attn1, A);
    make_m<<<dim3(192, 2), 192, 0, stream>>>(proj_w, A, M);

    // K4: out = M @ v, in-place on d_out
    gemm192<<<dim3(1024, 1, 2), 256, 0, stream>>>(
        M, out, out, 0, 192LL * 192, xBatch, xBatch);
}

// Round 5
// 1507.549 us; speedup vs baseline: 1.5892x; 1.3008x over previous
//
#include <hip/hip_runtime.h>
#include <math.h>

#define N_SP 65536   // h*w
#define IMG  256

// ---------------------------------------------------------------------------
// GEMM: C[row0+r, n] = sum_{c<192} W[(wrow0+row0+r)*192 + c] * X[c*N_SP + n]
// Block: 256 threads -> tile of 192 rows x 64 columns. Thread = 12 rows x 4 cols.
// K1 (qkv 1x1 conv) and K4 (fused M @ v, in-place on d_out).
// In-place safety (K4): block reads only cols [n0,n0+64) of X, writes same cols;
// __syncthreads() after last k-step orders reads before writes; blocks disjoint.
// X/C deliberately NOT __restrict__ (K4 aliases them).
// ---------------------------------------------------------------------------
__global__ __launch_bounds__(256) void gemm192(
    const float* __restrict__ W, const float* X, float* C,
    int wrow0, long long wBS, long long xBS, long long cBS)
{
    __shared__ float Wld[192][33];
    const int t   = threadIdx.x;
    const int cq  = t & 15;
    const int rg  = t >> 4;
    const int rbase = rg * 12;
    const long long n0 = (long long)blockIdx.x * 64;
    const int row0 = blockIdx.y * 192;
    const int b    = blockIdx.z;
    const float* Wb = W + (long long)b * wBS + (long long)(wrow0 + row0) * 192;
    const float* Xb = X + (long long)b * xBS;

    float acc[12][4];
    #pragma unroll
    for (int r = 0; r < 12; ++r) { acc[r][0]=0.f; acc[r][1]=0.f; acc[r][2]=0.f; acc[r][3]=0.f; }

    for (int c0 = 0; c0 < 192; c0 += 32) {
        #pragma unroll
        for (int i = 0; i < 24; ++i) {
            int id = t + i * 256;
            int rr = id >> 5, cc = id & 31;
            Wld[rr][cc] = Wb[rr * 192 + c0 + cc];
        }
        __syncthreads();
        #pragma unroll 8
        for (int cc = 0; cc < 32; ++cc) {
            const float4 xv = *(const float4*)(Xb + (long long)(c0 + cc) * N_SP + n0 + cq * 4);
            #pragma unroll
            for (int r = 0; r < 12; ++r) {
                float wv = Wld[rbase + r][cc];
                acc[r][0] = fmaf(wv, xv.x, acc[r][0]);
                acc[r][1] = fmaf(wv, xv.y, acc[r][1]);
                acc[r][2] = fmaf(wv, xv.z, acc[r][2]);
                acc[r][3] = fmaf(wv, xv.w, acc[r][3]);
            }
        }
        __syncthreads();
    }
    float* Cb = C + (long long)b * cBS + n0 + cq * 4;
    #pragma unroll
    for (int r = 0; r < 12; ++r) {
        float4 o; o.x = acc[r][0]; o.y = acc[r][1]; o.z = acc[r][2]; o.w = acc[r][3];
        *(float4*)(Cb + (long long)(row0 + rbase + r) * N_SP) = o;
    }
}

// ---------------------------------------------------------------------------
// dwconv: depthwise 3x3 on 4*gridDim.y channels. Channel c: reads src+c*N_SP,
// weights dww+c*9, writes dst+c*N_SP. Used for q,k (96 groups) and v (48 groups).
// Round-4 lesson: keep DW conv a pure streaming kernel (no fused reduction) --
// the fused version was stuck at 2 blocks/CU and latency-bound (VALUBusy 7%).
// ---------------------------------------------------------------------------
__global__ __launch_bounds__(256) void dwconv(
    const float* __restrict__ src, const float* __restrict__ dww, float* __restrict__ dst)
{
    const int t = threadIdx.x;
    const int tile = blockIdx.x, cg = blockIdx.y;
    const int ty0 = (tile >> 2) * 4, tx0 = (tile & 3) * 64;
    const int py = t >> 6, px = t & 63;
    const int gy = ty0 + py, gx = tx0 + px;

    int  yo[3], xo[3]; bool vy[3], vx[3];
    #pragma unroll
    for (int d = 0; d < 3; ++d) {
        int yy = gy + d - 1; vy[d] = (yy >= 0 && yy < IMG); yo[d] = yy * IMG;
        int xx = gx + d - 1; vx[d] = (xx >= 0 && xx < IMG); xo[d] = xx;
    }
    #pragma unroll
    for (int i = 0; i < 4; ++i) {
        const int c = cg * 4 + i;
        const float* base = src + ((long long)c << 16);
        const float* wp = dww + c * 9;
        float s = 0.f;
        #pragma unroll
        for (int dy = 0; dy < 3; ++dy) {
            if (vy[dy]) {
                #pragma unroll
                for (int dx = 0; dx < 3; ++dx) {
                    if (vx[dx]) s = fmaf(wp[dy * 3 + dx], base[yo[dy] + xo[dx]], s);
                }
            }
        }
        dst[((long long)c << 16) + gy * IMG + gx] = s;
    }
}

// ---------------------------------------------------------------------------
// gred: G/Sq/Sk partial reduction from post-DW q,k in global (qk = 384 ch:
// q at h*32+c, k at 192+h*32+c). Grid (128 chunks, 6 heads); block = 4 waves;
// wave covers 128 pixels; lane owns a 4x4 (c,d) tile, float4 (4-pixel) steps.
// Writes Gpart[(h*128+blk)*1088] = [1024 G][32 Sq][32 Sk]. No atomics.
// ---------------------------------------------------------------------------
__global__ __launch_bounds__(256) void gred(
    const float* __restrict__ qk, float* __restrict__ Gpart)
{
    __shared__ float red[4096];
    __shared__ float red2[256];
    const int t = threadIdx.x;
    const int blk = blockIdx.x, h = blockIdx.y;
    const int w = t >> 6, l = t & 63;
    const int cqd = l >> 3, dqd = l & 7;

    float acc[4][4];
    #pragma unroll
    for (int i = 0; i < 4; ++i) { acc[i][0]=0.f; acc[i][1]=0.f; acc[i][2]=0.f; acc[i][3]=0.f; }
    float sq[4] = {0.f,0.f,0.f,0.f}, sk[4] = {0.f,0.f,0.f,0.f};

    const float* qbase = qk + ((long long)(h * 32 + cqd * 4) << 16);
    const float* kbase = qk + ((long long)(192 + h * 32 + dqd * 4) << 16);
    const int n0 = blk * 512 + w * 128;

    for (int it = 0; it < 32; ++it) {
        const int n = n0 + it * 4;
        float4 qa[4], kb[4];
        #pragma unroll
        for (int i = 0; i < 4; ++i) qa[i] = *(const float4*)(qbase + ((long long)i << 16) + n);
        #pragma unroll
        for (int j = 0; j < 4; ++j) kb[j] = *(const float4*)(kbase + ((long long)j << 16) + n);
        #pragma unroll
        for (int i = 0; i < 4; ++i) {
            #pragma unroll
            for (int j = 0; j < 4; ++j) {
                acc[i][j] = fmaf(qa[i].x, kb[j].x, acc[i][j]);
                acc[i][j] = fmaf(qa[i].y, kb[j].y, acc[i][j]);
                acc[i][j] = fmaf(qa[i].z, kb[j].z, acc[i][j]);
                acc[i][j] = fmaf(qa[i].w, kb[j].w, acc[i][j]);
            }
        }
        if (dqd == 0) {
            #pragma unroll
            for (int i = 0; i < 4; ++i) {
                sq[i] = fmaf(qa[i].x, qa[i].x, sq[i]);
                sq[i] = fmaf(qa[i].y, qa[i].y, sq[i]);
                sq[i] = fmaf(qa[i].z, qa[i].z, sq[i]);
                sq[i] = fmaf(qa[i].w, qa[i].w, sq[i]);
            }
        }
        if (cqd == 0) {
            #pragma unroll
            for (int j = 0; j < 4; ++j) {
                sk[j] = fmaf(kb[j].x, kb[j].x, sk[j]);
                sk[j] = fmaf(kb[j].y, kb[j].y, sk[j]);
                sk[j] = fmaf(kb[j].z, kb[j].z, sk[j]);
                sk[j] = fmaf(kb[j].w, kb[j].w, sk[j]);
            }
        }
    }

    // cross-wave LDS reduction, one non-atomic partial write per block
    #pragma unroll
    for (int i = 0; i < 4; ++i) {
        #pragma unroll
        for (int j = 0; j < 4; ++j)
            red[w * 1024 + (cqd * 4 + i) * 32 + dqd * 4 + j] = acc[i][j];
    }
    if (dqd == 0) {
        #pragma unroll
        for (int i = 0; i < 4; ++i) red2[w * 32 + cqd * 4 + i] = sq[i];
    }
    if (cqd == 0) {
        #pragma unroll
        for (int j = 0; j < 4; ++j) red2[128 + w * 32 + dqd * 4 + j] = sk[j];
    }
    __syncthreads();

    float* Gp = Gpart + (long long)(h * 128 + blk) * 1088;
    #pragma unroll
    for (int i = 0; i < 4; ++i) {
        int slot = t + i * 256;
        Gp[slot] = red[slot] + red[1024 + slot] + red[2048 + slot] + red[3072 + slot];
    }
    if (t < 32) {
        Gp[1024 + t] = red2[t] + red2[32 + t] + red2[64 + t] + red2[96 + t];
    } else if (t < 64) {
        int c = t - 32;
        Gp[1056 + c] = red2[128 + c] + red2[160 + c] + red2[192 + c] + red2[224 + c];
    }
}

// ---------------------------------------------------------------------------
// reduce_g: sum 128 chunk-partials per head -> G, Sq, Sk (non-atomic, exact).
// ---------------------------------------------------------------------------
__global__ void reduce_g(const float* __restrict__ Gpart, float* __restrict__ G,
                         float* __restrict__ Sq, float* __restrict__ Sk, int bh0)
{
    const int h = blockIdx.x, t = threadIdx.x;
    const float* Gp = Gpart + (long long)h * 128 * 1088;
    const int bh = bh0 + h;
    #pragma unroll
    for (int i = 0; i < 5; ++i) {
        int slot = t + i * 256;
        if (slot >= 1088) break;
        float s = 0.f;
        for (int tl = 0; tl < 128; ++tl) s += Gp[(long long)tl * 1088 + slot];
        if (slot < 1024)      G[(long long)bh * 1024 + slot] = s;
        else if (slot < 1056) Sq[bh * 32 + (slot - 1024)] = s;
        else                  Sk[bh * 32 + (slot - 1056)] = s;
    }
}

// ---------------------------------------------------------------------------
// K3a: per (b,head): attn = G/(nq nk) * T; exact 16th-largest threshold per
// row; masked softmax; fold attn1. One thread per row c.
// ---------------------------------------------------------------------------
__global__ void attn_small(const float* __restrict__ G, const float* __restrict__ Sq,
                           const float* __restrict__ Sk, const float* __restrict__ temp,
                           const float* __restrict__ attn1, float* __restrict__ A)
{
    const int h = blockIdx.x, b = blockIdx.y, c = threadIdx.x;
    const int bh = b * 6 + h;
    const float* g = G + ((long long)bh * 32 + c) * 32;
    const float nq = fmaxf(sqrtf(Sq[bh * 32 + c]), 1e-12f);
    const float T  = temp[h];
    const float a1 = attn1[0];

    float a[32];
    #pragma unroll
    for (int d = 0; d < 32; ++d) {
        float nk = fmaxf(sqrtf(Sk[bh * 32 + d]), 1e-12f);
        a[d] = g[d] / (nq * nk) * T;
    }
    unsigned mask = 0u;
    float m = 0.f, kth = 0.f;
    for (int it = 0; it < 16; ++it) {
        float best = -3.4e38f; int bi = 0;
        #pragma unroll
        for (int d = 0; d < 32; ++d) {
            bool avail = ((mask >> d) & 1u) == 0u;
            if (avail && a[d] > best) { best = a[d]; bi = d; }
        }
        mask |= (1u << bi);
        if (it == 0) m = best;
        kth = best;
    }
    float denom = 0.f;
    #pragma unroll
    for (int d = 0; d < 32; ++d) if (a[d] >= kth) denom += expf(a[d] - m);
    const float inv = a1 / denom;
    float* Ar = A + ((long long)bh * 32 + c) * 32;
    #pragma unroll
    for (int d = 0; d < 32; ++d) Ar[d] = (a[d] >= kth) ? expf(a[d] - m) * inv : 0.f;
}

// ---------------------------------------------------------------------------
// K3b: M[b][o][hd*32+d] = sum_cq proj_w[o][hd*32+cq] * A[b][hd][cq][d]
// ---------------------------------------------------------------------------
__global__ void make_m(const float* __restrict__ proj_w, const float* __restrict__ A,
                       float* __restrict__ M)
{
    const int o = blockIdx.x, b = blockIdx.y, j = threadIdx.x;
    const int hd = j >> 5, d = j & 31;
    const float* pw = proj_w + o * 192 + hd * 32;
    const float* Ah = A + ((long long)(b * 6 + hd) * 32) * 32 + d;
    float s = 0.f;
    #pragma unroll
    for (int cq = 0; cq < 32; ++cq) s = fmaf(pw[cq], Ah[cq * 32], s);
    M[((long long)(b * 192 + o)) * 192 + j] = s;
}

// ---------------------------------------------------------------------------
extern "C" void kernel_launch(void* const* d_in, const int* in_sizes, int n_in,
                              void* d_out, int out_size, void* d_ws, size_t ws_size,
                              hipStream_t stream)
{
    const float* x      = (const float*)d_in[0];
    const float* qkv_w  = (const float*)d_in[1];
    const float* dww    = (const float*)d_in[2];
    const float* proj_w = (const float*)d_in[3];
    const float* temp   = (const float*)d_in[4];
    const float* attn1  = (const float*)d_in[5];
    float* out = (float*)d_out;
    float* wsf = (float*)d_ws;

    // ws layout (floats): tiny tensors first, then 96 MB staging buffer.
    float* G   = wsf;                 // 12,288
    float* Sq  = G + 12288;           // 384
    float* Sk  = Sq + 384;            // 384
    float* A   = Sk + 384;            // 12,288
    float* M   = A + 12288;           // 73,728
    float* buf = M + 73728;           // 384 ch x 256KB = 96 MB (q,k staging)

    const long long xBatch = 192LL * N_SP;
    // Scratch aliases (all stream-ordered, consumed before overwrite):
    //  qkpost = FULL d_out (384ch x 256KB = 96MB; v output written only in phase C)
    //  Gpart  = buf (pre-DW q,k dead once dwconv finished)
    float* qkpost = out;
    float* Gpart  = buf;

    // Phase A: per batch, attention-statistics path (q,k never persist)
    for (int b = 0; b < 2; ++b) {
        const float* xb = x + (long long)b * xBatch;
        gemm192<<<dim3(1024, 2, 1), 256, 0, stream>>>(qkv_w, xb, buf, 0, 0, 0, 0);
        dwconv<<<dim3(256, 96, 1), 256, 0, stream>>>(buf, dww, qkpost);
        gred<<<dim3(128, 6), 256, 0, stream>>>(qkpost, Gpart);
        reduce_g<<<dim3(6, 1), 256, 0, stream>>>(Gpart, G, Sq, Sk, b * 6);
    }

    // Phase B: tiny attention matrices + fused projection matrix
    attn_small<<<dim3(6, 2), 32, 0, stream>>>(G, Sq, Sk, temp, attn1, A);
    make_m<<<dim3(192, 2), 192, 0, stream>>>(proj_w, A, M);

    // Phase C: per batch, v path -> d_out
    for (int b = 0; b < 2; ++b) {
        const float* xb = x + (long long)b * xBatch;
        float* outb = out + (long long)b * xBatch;
        gemm192<<<dim3(1024, 1, 1), 256, 0, stream>>>(qkv_w, xb, buf, 384, 0, 0, 0);
        dwconv<<<dim3(256, 48, 1), 256, 0, stream>>>(buf, dww + 384 * 9, outb);
    }

    // Phase D: out = M @ v, in-place on d_out
    gemm192<<<dim3(1024, 1, 2), 256, 0, stream>>>(
        M, out, out, 0, 192LL * 192, xBatch, xBatch);
}

// Round 6
// 1152.777 us; speedup vs baseline: 2.0783x; 1.3078x over previous
//
#include <hip/hip_runtime.h>
#include <math.h>

#define N_SP 65536   // h*w
#define IMG  256

// ---------------------------------------------------------------------------
// fp32 tiled GEMM: C[row0+r, n] = sum_{c<192} W[(wrow0+...)*192+c] * X[c*N_SP+n]
// Tile: M=192, N=128, K-step=32. 256 threads: thread = (mg = t>>4)*12 rows x
// (ng = t&15)*8 cols -> 96 FMA per 12 W-broadcast-reads + 2 X-float4 reads.
// Round-5 lesson: previous version global-loaded each X float4 16x redundantly
// (VALUBusy 32%, 36 TF). Both operands now staged in LDS, coalesced, once.
// In-place safety (K4): block reads only X cols [n0,n0+128), all reads precede
// the final __syncthreads(), writes follow it; blocks touch disjoint columns.
// X/C deliberately NOT __restrict__ (K4 aliases them).
// ---------------------------------------------------------------------------
__global__ __launch_bounds__(256) void gemm_f32(
    const float* __restrict__ W, const float* X, float* C,
    int wrow0, long long wBS, long long xBS, long long cBS)
{
    __shared__ float Ws[192][36];    // stride 36: 16B-aligned float4 stores, low-conflict reads
    __shared__ float Xs[32][128];
    const int t  = threadIdx.x;
    const int mg = t >> 4;           // 16 m-groups x 12 rows
    const int ng = t & 15;           // 16 n-groups x 8 cols
    const long long n0 = (long long)blockIdx.x * 128;
    const int row0 = blockIdx.y * 192;
    const float* Wb = W + (long long)blockIdx.z * wBS + (long long)(wrow0 + row0) * 192;
    const float* Xb = X + (long long)blockIdx.z * xBS;

    float acc[12][8];
    #pragma unroll
    for (int r = 0; r < 12; ++r)
        #pragma unroll
        for (int j = 0; j < 8; ++j) acc[r][j] = 0.f;

    for (int c0 = 0; c0 < 192; c0 += 32) {
        // stage W tile: 192x32 = 1536 float4, coalesced
        #pragma unroll
        for (int i = 0; i < 6; ++i) {
            int id4 = t + i * 256;
            int rr = id4 >> 3, cc4 = (id4 & 7) * 4;
            float4 wv = *(const float4*)(Wb + rr * 192 + c0 + cc4);
            *(float4*)&Ws[rr][cc4] = wv;
        }
        // stage X tile: 32x128 = 1024 float4, coalesced
        #pragma unroll
        for (int i = 0; i < 4; ++i) {
            int id4 = t + i * 256;
            int rr = id4 >> 5, cc4 = (id4 & 31) * 4;
            float4 xv = *(const float4*)(Xb + (long long)(c0 + rr) * N_SP + n0 + cc4);
            *(float4*)&Xs[rr][cc4] = xv;
        }
        __syncthreads();
        #pragma unroll 4
        for (int k = 0; k < 32; ++k) {
            const float4 xv0 = *(const float4*)&Xs[k][ng * 8];
            const float4 xv1 = *(const float4*)&Xs[k][ng * 8 + 4];
            const float xr[8] = {xv0.x, xv0.y, xv0.z, xv0.w, xv1.x, xv1.y, xv1.z, xv1.w};
            #pragma unroll
            for (int r = 0; r < 12; ++r) {
                const float wv = Ws[mg * 12 + r][k];   // 16-lane broadcast
                #pragma unroll
                for (int j = 0; j < 8; ++j) acc[r][j] = fmaf(wv, xr[j], acc[r][j]);
            }
        }
        __syncthreads();
    }

    float* Cb = C + (long long)blockIdx.z * cBS + n0 + ng * 8;
    #pragma unroll
    for (int r = 0; r < 12; ++r) {
        const long long ro = (long long)(row0 + mg * 12 + r) * N_SP;
        float4 o0, o1;
        o0.x = acc[r][0]; o0.y = acc[r][1]; o0.z = acc[r][2]; o0.w = acc[r][3];
        o1.x = acc[r][4]; o1.y = acc[r][5]; o1.z = acc[r][6]; o1.w = acc[r][7];
        *(float4*)(Cb + ro)     = o0;
        *(float4*)(Cb + ro + 4) = o1;
    }
}

// ---------------------------------------------------------------------------
// dwconv: depthwise 3x3 on 4*gridDim.y channels. Channel c: reads src+c*N_SP,
// weights dww+c*9, writes dst+c*N_SP. Pure streaming kernel (round-4 lesson).
// ---------------------------------------------------------------------------
__global__ __launch_bounds__(256) void dwconv(
    const float* __restrict__ src, const float* __restrict__ dww, float* __restrict__ dst)
{
    const int t = threadIdx.x;
    const int tile = blockIdx.x, cg = blockIdx.y;
    const int ty0 = (tile >> 2) * 4, tx0 = (tile & 3) * 64;
    const int py = t >> 6, px = t & 63;
    const int gy = ty0 + py, gx = tx0 + px;

    int  yo[3], xo[3]; bool vy[3], vx[3];
    #pragma unroll
    for (int d = 0; d < 3; ++d) {
        int yy = gy + d - 1; vy[d] = (yy >= 0 && yy < IMG); yo[d] = yy * IMG;
        int xx = gx + d - 1; vx[d] = (xx >= 0 && xx < IMG); xo[d] = xx;
    }
    #pragma unroll
    for (int i = 0; i < 4; ++i) {
        const int c = cg * 4 + i;
        const float* base = src + ((long long)c << 16);
        const float* wp = dww + c * 9;
        float s = 0.f;
        #pragma unroll
        for (int dy = 0; dy < 3; ++dy) {
            if (vy[dy]) {
                #pragma unroll
                for (int dx = 0; dx < 3; ++dx) {
                    if (vx[dx]) s = fmaf(wp[dy * 3 + dx], base[yo[dy] + xo[dx]], s);
                }
            }
        }
        dst[((long long)c << 16) + gy * IMG + gx] = s;
    }
}

// ---------------------------------------------------------------------------
// gred: G/Sq/Sk partial reduction from post-DW q,k in global (qk = 384 ch:
// q at h*32+c, k at 192+h*32+c). Grid (128 chunks, 6 heads); block = 4 waves;
// wave covers 128 pixels; lane owns a 4x4 (c,d) tile, float4 (4-pixel) steps.
// Writes Gpart[(h*128+blk)*1088] = [1024 G][32 Sq][32 Sk]. No atomics.
// ---------------------------------------------------------------------------
__global__ __launch_bounds__(256) void gred(
    const float* __restrict__ qk, float* __restrict__ Gpart)
{
    __shared__ float red[4096];
    __shared__ float red2[256];
    const int t = threadIdx.x;
    const int blk = blockIdx.x, h = blockIdx.y;
    const int w = t >> 6, l = t & 63;
    const int cqd = l >> 3, dqd = l & 7;

    float acc[4][4];
    #pragma unroll
    for (int i = 0; i < 4; ++i) { acc[i][0]=0.f; acc[i][1]=0.f; acc[i][2]=0.f; acc[i][3]=0.f; }
    float sq[4] = {0.f,0.f,0.f,0.f}, sk[4] = {0.f,0.f,0.f,0.f};

    const float* qbase = qk + ((long long)(h * 32 + cqd * 4) << 16);
    const float* kbase = qk + ((long long)(192 + h * 32 + dqd * 4) << 16);
    const int n0 = blk * 512 + w * 128;

    for (int it = 0; it < 32; ++it) {
        const int n = n0 + it * 4;
        float4 qa[4], kb[4];
        #pragma unroll
        for (int i = 0; i < 4; ++i) qa[i] = *(const float4*)(qbase + ((long long)i << 16) + n);
        #pragma unroll
        for (int j = 0; j < 4; ++j) kb[j] = *(const float4*)(kbase + ((long long)j << 16) + n);
        #pragma unroll
        for (int i = 0; i < 4; ++i) {
            #pragma unroll
            for (int j = 0; j < 4; ++j) {
                acc[i][j] = fmaf(qa[i].x, kb[j].x, acc[i][j]);
                acc[i][j] = fmaf(qa[i].y, kb[j].y, acc[i][j]);
                acc[i][j] = fmaf(qa[i].z, kb[j].z, acc[i][j]);
                acc[i][j] = fmaf(qa[i].w, kb[j].w, acc[i][j]);
            }
        }
        if (dqd == 0) {
            #pragma unroll
            for (int i = 0; i < 4; ++i) {
                sq[i] = fmaf(qa[i].x, qa[i].x, sq[i]);
                sq[i] = fmaf(qa[i].y, qa[i].y, sq[i]);
                sq[i] = fmaf(qa[i].z, qa[i].z, sq[i]);
                sq[i] = fmaf(qa[i].w, qa[i].w, sq[i]);
            }
        }
        if (cqd == 0) {
            #pragma unroll
            for (int j = 0; j < 4; ++j) {
                sk[j] = fmaf(kb[j].x, kb[j].x, sk[j]);
                sk[j] = fmaf(kb[j].y, kb[j].y, sk[j]);
                sk[j] = fmaf(kb[j].z, kb[j].z, sk[j]);
                sk[j] = fmaf(kb[j].w, kb[j].w, sk[j]);
            }
        }
    }

    #pragma unroll
    for (int i = 0; i < 4; ++i) {
        #pragma unroll
        for (int j = 0; j < 4; ++j)
            red[w * 1024 + (cqd * 4 + i) * 32 + dqd * 4 + j] = acc[i][j];
    }
    if (dqd == 0) {
        #pragma unroll
        for (int i = 0; i < 4; ++i) red2[w * 32 + cqd * 4 + i] = sq[i];
    }
    if (cqd == 0) {
        #pragma unroll
        for (int j = 0; j < 4; ++j) red2[128 + w * 32 + dqd * 4 + j] = sk[j];
    }
    __syncthreads();

    float* Gp = Gpart + (long long)(h * 128 + blk) * 1088;
    #pragma unroll
    for (int i = 0; i < 4; ++i) {
        int slot = t + i * 256;
        Gp[slot] = red[slot] + red[1024 + slot] + red[2048 + slot] + red[3072 + slot];
    }
    if (t < 32) {
        Gp[1024 + t] = red2[t] + red2[32 + t] + red2[64 + t] + red2[96 + t];
    } else if (t < 64) {
        int c = t - 32;
        Gp[1056 + c] = red2[128 + c] + red2[160 + c] + red2[192 + c] + red2[224 + c];
    }
}

// ---------------------------------------------------------------------------
// reduce_g: sum 128 chunk-partials per head -> G, Sq, Sk (non-atomic, exact).
// ---------------------------------------------------------------------------
__global__ void reduce_g(const float* __restrict__ Gpart, float* __restrict__ G,
                         float* __restrict__ Sq, float* __restrict__ Sk, int bh0)
{
    const int h = blockIdx.x, t = threadIdx.x;
    const float* Gp = Gpart + (long long)h * 128 * 1088;
    const int bh = bh0 + h;
    #pragma unroll
    for (int i = 0; i < 5; ++i) {
        int slot = t + i * 256;
        if (slot >= 1088) break;
        float s = 0.f;
        for (int tl = 0; tl < 128; ++tl) s += Gp[(long long)tl * 1088 + slot];
        if (slot < 1024)      G[(long long)bh * 1024 + slot] = s;
        else if (slot < 1056) Sq[bh * 32 + (slot - 1024)] = s;
        else                  Sk[bh * 32 + (slot - 1056)] = s;
    }
}

// ---------------------------------------------------------------------------
// K3a: per (b,head): attn = G/(nq nk) * T; exact 16th-largest threshold per
// row; masked softmax; fold attn1. One thread per row c.
// ---------------------------------------------------------------------------
__global__ void attn_small(const float* __restrict__ G, const float* __restrict__ Sq,
                           const float* __restrict__ Sk, const float* __restrict__ temp,
                           const float* __restrict__ attn1, float* __restrict__ A)
{
    const int h = blockIdx.x, b = blockIdx.y, c = threadIdx.x;
    const int bh = b * 6 + h;
    const float* g = G + ((long long)bh * 32 + c) * 32;
    const float nq = fmaxf(sqrtf(Sq[bh * 32 + c]), 1e-12f);
    const float T  = temp[h];
    const float a1 = attn1[0];

    float a[32];
    #pragma unroll
    for (int d = 0; d < 32; ++d) {
        float nk = fmaxf(sqrtf(Sk[bh * 32 + d]), 1e-12f);
        a[d] = g[d] / (nq * nk) * T;
    }
    unsigned mask = 0u;
    float m = 0.f, kth = 0.f;
    for (int it = 0; it < 16; ++it) {
        float best = -3.4e38f; int bi = 0;
        #pragma unroll
        for (int d = 0; d < 32; ++d) {
            bool avail = ((mask >> d) & 1u) == 0u;
            if (avail && a[d] > best) { best = a[d]; bi = d; }
        }
        mask |= (1u << bi);
        if (it == 0) m = best;
        kth = best;
    }
    float denom = 0.f;
    #pragma unroll
    for (int d = 0; d < 32; ++d) if (a[d] >= kth) denom += expf(a[d] - m);
    const float inv = a1 / denom;
    float* Ar = A + ((long long)bh * 32 + c) * 32;
    #pragma unroll
    for (int d = 0; d < 32; ++d) Ar[d] = (a[d] >= kth) ? expf(a[d] - m) * inv : 0.f;
}

// ---------------------------------------------------------------------------
// K3b: M[b][o][hd*32+d] = sum_cq proj_w[o][hd*32+cq] * A[b][hd][cq][d]
// ---------------------------------------------------------------------------
__global__ void make_m(const float* __restrict__ proj_w, const float* __restrict__ A,
                       float* __restrict__ M)
{
    const int o = blockIdx.x, b = blockIdx.y, j = threadIdx.x;
    const int hd = j >> 5, d = j & 31;
    const float* pw = proj_w + o * 192 + hd * 32;
    const float* Ah = A + ((long long)(b * 6 + hd) * 32) * 32 + d;
    float s = 0.f;
    #pragma unroll
    for (int cq = 0; cq < 32; ++cq) s = fmaf(pw[cq], Ah[cq * 32], s);
    M[((long long)(b * 192 + o)) * 192 + j] = s;
}

// ---------------------------------------------------------------------------
extern "C" void kernel_launch(void* const* d_in, const int* in_sizes, int n_in,
                              void* d_out, int out_size, void* d_ws, size_t ws_size,
                              hipStream_t stream)
{
    const float* x      = (const float*)d_in[0];
    const float* qkv_w  = (const float*)d_in[1];
    const float* dww    = (const float*)d_in[2];
    const float* proj_w = (const float*)d_in[3];
    const float* temp   = (const float*)d_in[4];
    const float* attn1  = (const float*)d_in[5];
    float* out = (float*)d_out;
    float* wsf = (float*)d_ws;

    // ws layout (floats): tiny tensors first, then 96 MB staging buffer.
    float* G   = wsf;                 // 12,288
    float* Sq  = G + 12288;           // 384
    float* Sk  = Sq + 384;            // 384
    float* A   = Sk + 384;            // 12,288
    float* M   = A + 12288;           // 73,728
    float* buf = M + 73728;           // 384 ch x 256KB = 96 MB (q,k staging)

    const long long xBatch = 192LL * N_SP;
    // Scratch aliases (stream-ordered, consumed before overwrite):
    //  qkpost = FULL d_out (96MB; v output written only in phase C)
    //  Gpart  = buf (pre-DW q,k dead once dwconv finished)
    float* qkpost = out;
    float* Gpart  = buf;

    // Phase A: per batch, attention-statistics path (q,k never persist)
    for (int b = 0; b < 2; ++b) {
        const float* xb = x + (long long)b * xBatch;
        gemm_f32<<<dim3(512, 2, 1), 256, 0, stream>>>(qkv_w, xb, buf, 0, 0, 0, 0);
        dwconv<<<dim3(256, 96, 1), 256, 0, stream>>>(buf, dww, qkpost);
        gred<<<dim3(128, 6), 256, 0, stream>>>(qkpost, Gpart);
        reduce_g<<<dim3(6, 1), 256, 0, stream>>>(Gpart, G, Sq, Sk, b * 6);
    }

    // Phase B: tiny attention matrices + fused projection matrix
    attn_small<<<dim3(6, 2), 32, 0, stream>>>(G, Sq, Sk, temp, attn1, A);
    make_m<<<dim3(192, 2), 192, 0, stream>>>(proj_w, A, M);

    // Phase C: per batch, v path -> d_out
    for (int b = 0; b < 2; ++b) {
        const float* xb = x + (long long)b * xBatch;
        float* outb = out + (long long)b * xBatch;
        gemm_f32<<<dim3(512, 1, 1), 256, 0, stream>>>(qkv_w, xb, buf, 384, 0, 0, 0);
        dwconv<<<dim3(256, 48, 1), 256, 0, stream>>>(buf, dww + 384 * 9, outb);
    }

    // Phase D: out = M @ v, in-place on d_out
    gemm_f32<<<dim3(512, 1, 2), 256, 0, stream>>>(
        M, out, out, 0, 192LL * 192, xBatch, xBatch);
}

// Round 7
// 999.956 us; speedup vs baseline: 2.3960x; 1.1528x over previous
//
#include <hip/hip_runtime.h>
#include <math.h>

#define N_SP 65536   // h*w
#define IMG  256

typedef __attribute__((ext_vector_type(8))) short s16x8;
typedef __attribute__((ext_vector_type(4))) float f32x4;

// RNE fp32->bf16 (bit version, deterministic) and back
__device__ inline ushort f2bf(float f) {
    uint u = __float_as_uint(f);
    return (ushort)((u + 0x7FFFu + ((u >> 16) & 1u)) >> 16);
}
__device__ inline float bf2f(ushort h) { return __uint_as_float(((uint)h) << 16); }
__device__ inline uint pk2(ushort a, ushort b) { return (uint)a | ((uint)b << 16); }

// ---------------------------------------------------------------------------
// transp_conv: src fp32 [192][65536] -> hi/lo bf16 planes TRANSPOSED [65536][192].
// (MFMA B-operand wants the contraction dim contiguous per lane.)
// Tile 32c x 64n via LDS. Used for x (per batch) and post-DW v.
// ---------------------------------------------------------------------------
__global__ __launch_bounds__(256) void transp_conv(
    const float* __restrict__ src, ushort* __restrict__ hi, ushort* __restrict__ lo)
{
    __shared__ float T[32][65];
    const int t = threadIdx.x;
    const int n0 = blockIdx.x * 64, c0 = blockIdx.y * 32;
    {
        const int cb = t >> 6, n = t & 63;
        #pragma unroll
        for (int i = 0; i < 8; ++i) {
            const int c = cb + i * 4;
            T[c][n] = src[(long long)(c0 + c) * N_SP + n0 + n];
        }
    }
    __syncthreads();
    const int n = t >> 2, cq = (t & 3) * 8;
    float v[8];
    #pragma unroll
    for (int j = 0; j < 8; ++j) v[j] = T[cq + j][n];
    ushort h[8], l[8];
    #pragma unroll
    for (int j = 0; j < 8; ++j) { h[j] = f2bf(v[j]); l[j] = f2bf(v[j] - bf2f(h[j])); }
    uint4 H, L;
    H.x = pk2(h[0], h[1]); H.y = pk2(h[2], h[3]); H.z = pk2(h[4], h[5]); H.w = pk2(h[6], h[7]);
    L.x = pk2(l[0], l[1]); L.y = pk2(l[2], l[3]); L.z = pk2(l[4], l[5]); L.w = pk2(l[6], l[7]);
    const long long o = (long long)(n0 + n) * 192 + c0 + cq;
    *(uint4*)(hi + o) = H;
    *(uint4*)(lo + o) = L;
}

// ---------------------------------------------------------------------------
// gemm_mfma: C[m][n] = sum_k Wf[wrow0+m][k] * X[k][n], K=192, split-bf16:
// C = Whi*Xhi + Whi*Xlo + Wlo*Xhi (lo*lo dropped, ~1e-5 rel).
// A (W) converted hi/lo in-kernel during LDS staging (fp32 source, ld=192).
// B from pre-transposed planes XtHi/XtLo [n][192].
// Tile M=64 x N=256, 4 waves (wave = 64x64 = 4x4 16x16 frags), K-step 32.
// Same k-slot map (k = g*8+s) for A and B => any HW k-permutation cancels.
// C/D layout (m89-verified): col = lane&15, row = (lane>>4)*4 + j.
// ---------------------------------------------------------------------------
__global__ __launch_bounds__(256) void gemm_mfma(
    const float* __restrict__ Wf, int wrow0,
    const ushort* __restrict__ XtHi, const ushort* __restrict__ XtLo,
    float* __restrict__ C)
{
    __shared__ ushort WsH[64][40], WsL[64][40];   // pad 40: spreads banks
    __shared__ ushort XsH[256][32], XsL[256][32]; // stride 32: perfect-linear reads
    const int t  = threadIdx.x;
    const int wv = t >> 6, l = t & 63;
    const int lc = l & 15, lg = l >> 4;
    const int m0 = blockIdx.y * 64;
    const long long n0 = (long long)blockIdx.x * 256;

    f32x4 acc[4][4];
    #pragma unroll
    for (int i = 0; i < 4; ++i)
        #pragma unroll
        for (int j = 0; j < 4; ++j) acc[i][j] = (f32x4)(0.f);

    const int ar = t >> 2, ak = (t & 3) * 8;   // A staging: row, k-offset

    for (int kc = 0; kc < 192; kc += 32) {
        // stage A: 64x32 fp32 -> hi/lo bf16 (8 elems/thread)
        {
            const float* wp = Wf + (long long)(wrow0 + m0 + ar) * 192 + kc + ak;
            const float4 a0 = *(const float4*)wp;
            const float4 a1 = *(const float4*)(wp + 4);
            const float v[8] = {a0.x, a0.y, a0.z, a0.w, a1.x, a1.y, a1.z, a1.w};
            ushort h[8], lo_[8];
            #pragma unroll
            for (int j = 0; j < 8; ++j) { h[j] = f2bf(v[j]); lo_[j] = f2bf(v[j] - bf2f(h[j])); }
            uint4 H, L;
            H.x = pk2(h[0],h[1]); H.y = pk2(h[2],h[3]); H.z = pk2(h[4],h[5]); H.w = pk2(h[6],h[7]);
            L.x = pk2(lo_[0],lo_[1]); L.y = pk2(lo_[2],lo_[3]); L.z = pk2(lo_[4],lo_[5]); L.w = pk2(lo_[6],lo_[7]);
            *(uint4*)&WsH[ar][ak] = H;
            *(uint4*)&WsL[ar][ak] = L;
        }
        // stage X: 256x32 bf16 per plane (4x 16B chunks/thread/plane)
        #pragma unroll
        for (int i = 0; i < 4; ++i) {
            const int chunk = t + i * 256;
            const int r = chunk >> 2, ko = (chunk & 3) * 8;
            const long long g = (n0 + r) * 192 + kc + ko;
            *(uint4*)&XsH[r][ko] = *(const uint4*)(XtHi + g);
            *(uint4*)&XsL[r][ko] = *(const uint4*)(XtLo + g);
        }
        __syncthreads();

        s16x8 ah[4], al[4];
        #pragma unroll
        for (int mf = 0; mf < 4; ++mf) {
            ah[mf] = *(const s16x8*)&WsH[mf * 16 + lc][lg * 8];
            al[mf] = *(const s16x8*)&WsL[mf * 16 + lc][lg * 8];
        }
        #pragma unroll
        for (int nf = 0; nf < 4; ++nf) {
            const int nr = wv * 64 + nf * 16 + lc;
            const s16x8 bh = *(const s16x8*)&XsH[nr][lg * 8];
            const s16x8 bl = *(const s16x8*)&XsL[nr][lg * 8];
            #pragma unroll
            for (int mf = 0; mf < 4; ++mf) {
                acc[mf][nf] = __builtin_amdgcn_mfma_f32_16x16x32_bf16(ah[mf], bh, acc[mf][nf], 0, 0, 0);
                acc[mf][nf] = __builtin_amdgcn_mfma_f32_16x16x32_bf16(ah[mf], bl, acc[mf][nf], 0, 0, 0);
                acc[mf][nf] = __builtin_amdgcn_mfma_f32_16x16x32_bf16(al[mf], bh, acc[mf][nf], 0, 0, 0);
            }
        }
        __syncthreads();
    }

    #pragma unroll
    for (int mf = 0; mf < 4; ++mf)
        #pragma unroll
        for (int nf = 0; nf < 4; ++nf) {
            const long long nn = n0 + wv * 64 + nf * 16 + lc;
            #pragma unroll
            for (int j = 0; j < 4; ++j)
                C[(long long)(m0 + mf * 16 + lg * 4 + j) * N_SP + nn] = acc[mf][nf][j];
        }
}

// ---------------------------------------------------------------------------
// dwconv: depthwise 3x3 on 4*gridDim.y channels (pure streaming; round-4 lesson).
// ---------------------------------------------------------------------------
__global__ __launch_bounds__(256) void dwconv(
    const float* __restrict__ src, const float* __restrict__ dww, float* __restrict__ dst)
{
    const int t = threadIdx.x;
    const int tile = blockIdx.x, cg = blockIdx.y;
    const int ty0 = (tile >> 2) * 4, tx0 = (tile & 3) * 64;
    const int py = t >> 6, px = t & 63;
    const int gy = ty0 + py, gx = tx0 + px;

    int  yo[3], xo[3]; bool vy[3], vx[3];
    #pragma unroll
    for (int d = 0; d < 3; ++d) {
        int yy = gy + d - 1; vy[d] = (yy >= 0 && yy < IMG); yo[d] = yy * IMG;
        int xx = gx + d - 1; vx[d] = (xx >= 0 && xx < IMG); xo[d] = xx;
    }
    #pragma unroll
    for (int i = 0; i < 4; ++i) {
        const int c = cg * 4 + i;
        const float* base = src + ((long long)c << 16);
        const float* wp = dww + c * 9;
        float s = 0.f;
        #pragma unroll
        for (int dy = 0; dy < 3; ++dy) {
            if (vy[dy]) {
                #pragma unroll
                for (int dx = 0; dx < 3; ++dx) {
                    if (vx[dx]) s = fmaf(wp[dy * 3 + dx], base[yo[dy] + xo[dx]], s);
                }
            }
        }
        dst[((long long)c << 16) + gy * IMG + gx] = s;
    }
}

// ---------------------------------------------------------------------------
// gred: G/Sq/Sk partials from post-DW q (ch 0..191) and k (ch 0..191, separate
// buffers). Grid (128 chunks, 6 heads); lane owns 4x4 (c,d); no atomics.
// ---------------------------------------------------------------------------
__global__ __launch_bounds__(256) void gred(
    const float* __restrict__ q, const float* __restrict__ k, float* __restrict__ Gpart)
{
    __shared__ float red[4096];
    __shared__ float red2[256];
    const int t = threadIdx.x;
    const int blk = blockIdx.x, h = blockIdx.y;
    const int w = t >> 6, l = t & 63;
    const int cqd = l >> 3, dqd = l & 7;

    float acc[4][4];
    #pragma unroll
    for (int i = 0; i < 4; ++i) { acc[i][0]=0.f; acc[i][1]=0.f; acc[i][2]=0.f; acc[i][3]=0.f; }
    float sq[4] = {0.f,0.f,0.f,0.f}, sk[4] = {0.f,0.f,0.f,0.f};

    const float* qbase = q + ((long long)(h * 32 + cqd * 4) << 16);
    const float* kbase = k + ((long long)(h * 32 + dqd * 4) << 16);
    const int n0 = blk * 512 + w * 128;

    for (int it = 0; it < 32; ++it) {
        const int n = n0 + it * 4;
        float4 qa[4], kb[4];
        #pragma unroll
        for (int i = 0; i < 4; ++i) qa[i] = *(const float4*)(qbase + ((long long)i << 16) + n);
        #pragma unroll
        for (int j = 0; j < 4; ++j) kb[j] = *(const float4*)(kbase + ((long long)j << 16) + n);
        #pragma unroll
        for (int i = 0; i < 4; ++i) {
            #pragma unroll
            for (int j = 0; j < 4; ++j) {
                acc[i][j] = fmaf(qa[i].x, kb[j].x, acc[i][j]);
                acc[i][j] = fmaf(qa[i].y, kb[j].y, acc[i][j]);
                acc[i][j] = fmaf(qa[i].z, kb[j].z, acc[i][j]);
                acc[i][j] = fmaf(qa[i].w, kb[j].w, acc[i][j]);
            }
        }
        if (dqd == 0) {
            #pragma unroll
            for (int i = 0; i < 4; ++i) {
                sq[i] = fmaf(qa[i].x, qa[i].x, sq[i]);
                sq[i] = fmaf(qa[i].y, qa[i].y, sq[i]);
                sq[i] = fmaf(qa[i].z, qa[i].z, sq[i]);
                sq[i] = fmaf(qa[i].w, qa[i].w, sq[i]);
            }
        }
        if (cqd == 0) {
            #pragma unroll
            for (int j = 0; j < 4; ++j) {
                sk[j] = fmaf(kb[j].x, kb[j].x, sk[j]);
                sk[j] = fmaf(kb[j].y, kb[j].y, sk[j]);
                sk[j] = fmaf(kb[j].z, kb[j].z, sk[j]);
                sk[j] = fmaf(kb[j].w, kb[j].w, sk[j]);
            }
        }
    }

    #pragma unroll
    for (int i = 0; i < 4; ++i) {
        #pragma unroll
        for (int j = 0; j < 4; ++j)
            red[w * 1024 + (cqd * 4 + i) * 32 + dqd * 4 + j] = acc[i][j];
    }
    if (dqd == 0) {
        #pragma unroll
        for (int i = 0; i < 4; ++i) red2[w * 32 + cqd * 4 + i] = sq[i];
    }
    if (cqd == 0) {
        #pragma unroll
        for (int j = 0; j < 4; ++j) red2[128 + w * 32 + dqd * 4 + j] = sk[j];
    }
    __syncthreads();

    float* Gp = Gpart + (long long)(h * 128 + blk) * 1088;
    #pragma unroll
    for (int i = 0; i < 4; ++i) {
        int slot = t + i * 256;
        Gp[slot] = red[slot] + red[1024 + slot] + red[2048 + slot] + red[3072 + slot];
    }
    if (t < 32) {
        Gp[1024 + t] = red2[t] + red2[32 + t] + red2[64 + t] + red2[96 + t];
    } else if (t < 64) {
        int c = t - 32;
        Gp[1056 + c] = red2[128 + c] + red2[160 + c] + red2[192 + c] + red2[224 + c];
    }
}

__global__ void reduce_g(const float* __restrict__ Gpart, float* __restrict__ G,
                         float* __restrict__ Sq, float* __restrict__ Sk, int bh0)
{
    const int h = blockIdx.x, t = threadIdx.x;
    const float* Gp = Gpart + (long long)h * 128 * 1088;
    const int bh = bh0 + h;
    #pragma unroll
    for (int i = 0; i < 5; ++i) {
        int slot = t + i * 256;
        if (slot >= 1088) break;
        float s = 0.f;
        for (int tl = 0; tl < 128; ++tl) s += Gp[(long long)tl * 1088 + slot];
        if (slot < 1024)      G[(long long)bh * 1024 + slot] = s;
        else if (slot < 1056) Sq[bh * 32 + (slot - 1024)] = s;
        else                  Sk[bh * 32 + (slot - 1056)] = s;
    }
}

__global__ void attn_small(const float* __restrict__ G, const float* __restrict__ Sq,
                           const float* __restrict__ Sk, const float* __restrict__ temp,
                           const float* __restrict__ attn1, float* __restrict__ A)
{
    const int h = blockIdx.x, b = blockIdx.y, c = threadIdx.x;
    const int bh = b * 6 + h;
    const float* g = G + ((long long)bh * 32 + c) * 32;
    const float nq = fmaxf(sqrtf(Sq[bh * 32 + c]), 1e-12f);
    const float T  = temp[h];
    const float a1 = attn1[0];

    float a[32];
    #pragma unroll
    for (int d = 0; d < 32; ++d) {
        float nk = fmaxf(sqrtf(Sk[bh * 32 + d]), 1e-12f);
        a[d] = g[d] / (nq * nk) * T;
    }
    unsigned mask = 0u;
    float m = 0.f, kth = 0.f;
    for (int it = 0; it < 16; ++it) {
        float best = -3.4e38f; int bi = 0;
        #pragma unroll
        for (int d = 0; d < 32; ++d) {
            bool avail = ((mask >> d) & 1u) == 0u;
            if (avail && a[d] > best) { best = a[d]; bi = d; }
        }
        mask |= (1u << bi);
        if (it == 0) m = best;
        kth = best;
    }
    float denom = 0.f;
    #pragma unroll
    for (int d = 0; d < 32; ++d) if (a[d] >= kth) denom += expf(a[d] - m);
    const float inv = a1 / denom;
    float* Ar = A + ((long long)bh * 32 + c) * 32;
    #pragma unroll
    for (int d = 0; d < 32; ++d) Ar[d] = (a[d] >= kth) ? expf(a[d] - m) * inv : 0.f;
}

__global__ void make_m(const float* __restrict__ proj_w, const float* __restrict__ A,
                       float* __restrict__ M)
{
    const int o = blockIdx.x, b = blockIdx.y, j = threadIdx.x;
    const int hd = j >> 5, d = j & 31;
    const float* pw = proj_w + o * 192 + hd * 32;
    const float* Ah = A + ((long long)(b * 6 + hd) * 32) * 32 + d;
    float s = 0.f;
    #pragma unroll
    for (int cq = 0; cq < 32; ++cq) s = fmaf(pw[cq], Ah[cq * 32], s);
    M[((long long)(b * 192 + o)) * 192 + j] = s;
}

// ---------------------------------------------------------------------------
extern "C" void kernel_launch(void* const* d_in, const int* in_sizes, int n_in,
                              void* d_out, int out_size, void* d_ws, size_t ws_size,
                              hipStream_t stream)
{
    const float* x      = (const float*)d_in[0];
    const float* qkv_w  = (const float*)d_in[1];
    const float* dww    = (const float*)d_in[2];
    const float* proj_w = (const float*)d_in[3];
    const float* temp   = (const float*)d_in[4];
    const float* attn1  = (const float*)d_in[5];
    float* out = (float*)d_out;
    float* wsf = (float*)d_ws;

    // ws layout (floats) -- total = proven-safe 101,059,584 bytes
    float* G   = wsf;                 // 12,288
    float* Sq  = G + 12288;           // 384
    float* Sk  = Sq + 384;            // 384
    float* A   = Sk + 384;            // 12,288
    float* Mm  = A + 12288;           // 73,728
    float* buf = Mm + 73728;          // 96 MiB

    const long long PL = 12582912LL;  // floats per 48 MiB region
    float* W1 = buf;                  // ws halves
    float* W2 = buf + PL;
    float* R1 = out;                  // d_out halves (= batch regions)
    float* R2 = out + PL;

    // Phase S: attention statistics per batch.
    //  Xt(x) -> R1 ; K1qk -> buf (q@W1, k@W2) ; dw-q: W1->R2 ; dw-k: W2->W1 ;
    //  gred(R2, W1) -> Gpart@W2 ; reduce_g.
    for (int b = 0; b < 2; ++b) {
        const float* xb = x + (long long)b * PL;
        ushort* XtH = (ushort*)R1;
        ushort* XtL = (ushort*)R1 + PL;
        transp_conv<<<dim3(1024, 6), 256, 0, stream>>>(xb, XtH, XtL);
        gemm_mfma<<<dim3(256, 6), 256, 0, stream>>>(qkv_w, 0, XtH, XtL, buf);
        dwconv<<<dim3(256, 48), 256, 0, stream>>>(W1, dww, R2);            // q post
        dwconv<<<dim3(256, 48), 256, 0, stream>>>(W2, dww + 192 * 9, W1);  // k post
        gred<<<dim3(128, 6), 256, 0, stream>>>(R2, W1, W2);
        reduce_g<<<dim3(6, 1), 256, 0, stream>>>(W2, G, Sq, Sk, b * 6);
    }

    // Phase B: tiny attention matrices + fused projection matrix
    attn_small<<<dim3(6, 2), 32, 0, stream>>>(G, Sq, Sk, temp, attn1, A);
    make_m<<<dim3(192, 2), 192, 0, stream>>>(proj_w, A, Mm);

    // Phase V: v path per batch: Xt(x)->W1 ; K1v -> W2 ; dwconv-v -> d_out[b]
    for (int b = 0; b < 2; ++b) {
        const float* xb = x + (long long)b * PL;
        ushort* XtH = (ushort*)W1;
        ushort* XtL = (ushort*)W1 + PL;
        transp_conv<<<dim3(1024, 6), 256, 0, stream>>>(xb, XtH, XtL);
        gemm_mfma<<<dim3(256, 3), 256, 0, stream>>>(qkv_w, 384, XtH, XtL, W2);
        dwconv<<<dim3(256, 48), 256, 0, stream>>>(W2, dww + 384 * 9, out + (long long)b * PL);
    }

    // Phase K4: per batch: vT(v-post)->W1 ; out[b] = M_b @ v (reads ws, writes d_out)
    for (int b = 0; b < 2; ++b) {
        float* outb = out + (long long)b * PL;
        ushort* vTH = (ushort*)W1;
        ushort* vTL = (ushort*)W1 + PL;
        transp_conv<<<dim3(1024, 6), 256, 0, stream>>>(outb, vTH, vTL);
        gemm_mfma<<<dim3(256, 3), 256, 0, stream>>>(Mm + (long long)b * 36864, 0, vTH, vTL, outb);
    }
}

// Round 8
// 749.947 us; speedup vs baseline: 3.1947x; 1.3334x over previous
//
#include <hip/hip_runtime.h>
#include <math.h>

#define N_SP 65536   // h*w
#define IMG  256

typedef __attribute__((ext_vector_type(8))) short s16x8;
typedef __attribute__((ext_vector_type(4))) float f32x4;

// RNE fp32->bf16 (bit version, deterministic) and back
__device__ inline ushort f2bf(float f) {
    uint u = __float_as_uint(f);
    return (ushort)((u + 0x7FFFu + ((u >> 16) & 1u)) >> 16);
}
__device__ inline float bf2f(ushort h) { return __uint_as_float(((uint)h) << 16); }
__device__ inline uint pk2(ushort a, ushort b) { return (uint)a | ((uint)b << 16); }

// ---------------------------------------------------------------------------
// transp_conv: src fp32 [192][65536] -> hi/lo bf16 planes TRANSPOSED [65536][192].
// Tile 32c x 64n via LDS. Used for x (per batch) and post-DW v.
// ---------------------------------------------------------------------------
__global__ __launch_bounds__(256) void transp_conv(
    const float* __restrict__ src, ushort* __restrict__ hi, ushort* __restrict__ lo)
{
    __shared__ float T[32][65];
    const int t = threadIdx.x;
    const int n0 = blockIdx.x * 64, c0 = blockIdx.y * 32;
    {
        const int cb = t >> 6, n = t & 63;
        #pragma unroll
        for (int i = 0; i < 8; ++i) {
            const int c = cb + i * 4;
            T[c][n] = src[(long long)(c0 + c) * N_SP + n0 + n];
        }
    }
    __syncthreads();
    const int n = t >> 2, cq = (t & 3) * 8;
    float v[8];
    #pragma unroll
    for (int j = 0; j < 8; ++j) v[j] = T[cq + j][n];
    ushort h[8], l[8];
    #pragma unroll
    for (int j = 0; j < 8; ++j) { h[j] = f2bf(v[j]); l[j] = f2bf(v[j] - bf2f(h[j])); }
    uint4 H, L;
    H.x = pk2(h[0], h[1]); H.y = pk2(h[2], h[3]); H.z = pk2(h[4], h[5]); H.w = pk2(h[6], h[7]);
    L.x = pk2(l[0], l[1]); L.y = pk2(l[2], l[3]); L.z = pk2(l[4], l[5]); L.w = pk2(l[6], l[7]);
    const long long o = (long long)(n0 + n) * 192 + c0 + cq;
    *(uint4*)(hi + o) = H;
    *(uint4*)(lo + o) = L;
}

// ---------------------------------------------------------------------------
// gemm_mfma: C[m][n] = sum_k Wf[wrow0+m][k] * X[k][n], K=192, split-bf16:
// C = Whi*Xhi + Whi*Xlo + Wlo*Xhi (lo*lo dropped, ~1e-5 rel).
// A (W) converted hi/lo in-kernel during LDS staging (fp32 source, ld=192).
// B from pre-transposed planes XtHi/XtLo [n][192].
// Tile M=64 x N=256, 4 waves, K-step 32. Same k-slot map for A and B =>
// any HW k-permutation cancels. C/D (m89): col=lane&15, row=(lane>>4)*4+j.
// ---------------------------------------------------------------------------
__global__ __launch_bounds__(256) void gemm_mfma(
    const float* __restrict__ Wf, int wrow0,
    const ushort* __restrict__ XtHi, const ushort* __restrict__ XtLo,
    float* __restrict__ C)
{
    __shared__ ushort WsH[64][40], WsL[64][40];
    __shared__ ushort XsH[256][32], XsL[256][32];
    const int t  = threadIdx.x;
    const int wv = t >> 6, l = t & 63;
    const int lc = l & 15, lg = l >> 4;
    const int m0 = blockIdx.y * 64;
    const long long n0 = (long long)blockIdx.x * 256;

    f32x4 acc[4][4];
    #pragma unroll
    for (int i = 0; i < 4; ++i)
        #pragma unroll
        for (int j = 0; j < 4; ++j) acc[i][j] = (f32x4)(0.f);

    const int ar = t >> 2, ak = (t & 3) * 8;

    for (int kc = 0; kc < 192; kc += 32) {
        {
            const float* wp = Wf + (long long)(wrow0 + m0 + ar) * 192 + kc + ak;
            const float4 a0 = *(const float4*)wp;
            const float4 a1 = *(const float4*)(wp + 4);
            const float v[8] = {a0.x, a0.y, a0.z, a0.w, a1.x, a1.y, a1.z, a1.w};
            ushort h[8], lo_[8];
            #pragma unroll
            for (int j = 0; j < 8; ++j) { h[j] = f2bf(v[j]); lo_[j] = f2bf(v[j] - bf2f(h[j])); }
            uint4 H, L;
            H.x = pk2(h[0],h[1]); H.y = pk2(h[2],h[3]); H.z = pk2(h[4],h[5]); H.w = pk2(h[6],h[7]);
            L.x = pk2(lo_[0],lo_[1]); L.y = pk2(lo_[2],lo_[3]); L.z = pk2(lo_[4],lo_[5]); L.w = pk2(lo_[6],lo_[7]);
            *(uint4*)&WsH[ar][ak] = H;
            *(uint4*)&WsL[ar][ak] = L;
        }
        #pragma unroll
        for (int i = 0; i < 4; ++i) {
            const int chunk = t + i * 256;
            const int r = chunk >> 2, ko = (chunk & 3) * 8;
            const long long g = (n0 + r) * 192 + kc + ko;
            *(uint4*)&XsH[r][ko] = *(const uint4*)(XtHi + g);
            *(uint4*)&XsL[r][ko] = *(const uint4*)(XtLo + g);
        }
        __syncthreads();

        s16x8 ah[4], al[4];
        #pragma unroll
        for (int mf = 0; mf < 4; ++mf) {
            ah[mf] = *(const s16x8*)&WsH[mf * 16 + lc][lg * 8];
            al[mf] = *(const s16x8*)&WsL[mf * 16 + lc][lg * 8];
        }
        #pragma unroll
        for (int nf = 0; nf < 4; ++nf) {
            const int nr = wv * 64 + nf * 16 + lc;
            const s16x8 bh = *(const s16x8*)&XsH[nr][lg * 8];
            const s16x8 bl = *(const s16x8*)&XsL[nr][lg * 8];
            #pragma unroll
            for (int mf = 0; mf < 4; ++mf) {
                acc[mf][nf] = __builtin_amdgcn_mfma_f32_16x16x32_bf16(ah[mf], bh, acc[mf][nf], 0, 0, 0);
                acc[mf][nf] = __builtin_amdgcn_mfma_f32_16x16x32_bf16(ah[mf], bl, acc[mf][nf], 0, 0, 0);
                acc[mf][nf] = __builtin_amdgcn_mfma_f32_16x16x32_bf16(al[mf], bh, acc[mf][nf], 0, 0, 0);
            }
        }
        __syncthreads();
    }

    #pragma unroll
    for (int mf = 0; mf < 4; ++mf)
        #pragma unroll
        for (int nf = 0; nf < 4; ++nf) {
            const long long nn = n0 + wv * 64 + nf * 16 + lc;
            #pragma unroll
            for (int j = 0; j < 4; ++j)
                C[(long long)(m0 + mf * 16 + lg * 4 + j) * N_SP + nn] = acc[mf][nf][j];
        }
}

// ---------------------------------------------------------------------------
// dwconv8: depthwise 3x3, register-shift, 8 px x 4 channels per thread.
// Round-7 lesson: scalar version was VMEM-instruction-issue bound (40 VMEM for
// 4 px -> 51us floor). Now 56 VMEM per 32 px via float4 loads. Halo rows are
// handled by clamped (in-bounds) loads with zeroed weights -> no divergence.
// Grid: (32, NCH/4). Strip s = bx*256+t: y = s>>5, x8 = (s&31)*8.
// ---------------------------------------------------------------------------
__global__ __launch_bounds__(256) void dwconv8(
    const float* __restrict__ src, const float* __restrict__ dww, float* __restrict__ dst)
{
    const int t = threadIdx.x;
    const int s = blockIdx.x * 256 + t;
    const int y = s >> 5;
    const int x8 = (s & 31) * 8;
    const int cg = blockIdx.y;

    const int xl = (x8 == 0) ? 0 : x8 - 4;      // clamped halo loads (16B aligned)
    const int xr = (x8 == 248) ? 248 : x8 + 8;

    #pragma unroll
    for (int i = 0; i < 4; ++i) {
        const int c = cg * 4 + i;
        const float* base = src + ((long long)c << 16);
        const float* wp = dww + c * 9;
        float acc[8];
        #pragma unroll
        for (int j = 0; j < 8; ++j) acc[j] = 0.f;
        #pragma unroll
        for (int dy = 0; dy < 3; ++dy) {
            const int yy = y + dy - 1;
            const bool vld = (yy >= 0 && yy < IMG);
            const float* row = base + (vld ? yy : y) * IMG;
            const float w0 = vld ? wp[dy * 3 + 0] : 0.f;
            const float w1 = vld ? wp[dy * 3 + 1] : 0.f;
            const float w2 = vld ? wp[dy * 3 + 2] : 0.f;
            const float4 Lq = *(const float4*)(row + xl);
            const float4 M0 = *(const float4*)(row + x8);
            const float4 M1 = *(const float4*)(row + x8 + 4);
            const float4 Rq = *(const float4*)(row + xr);
            float vv[10];
            vv[0] = (x8 == 0) ? 0.f : Lq.w;
            vv[1] = M0.x; vv[2] = M0.y; vv[3] = M0.z; vv[4] = M0.w;
            vv[5] = M1.x; vv[6] = M1.y; vv[7] = M1.z; vv[8] = M1.w;
            vv[9] = (x8 == 248) ? 0.f : Rq.x;
            #pragma unroll
            for (int j = 0; j < 8; ++j)
                acc[j] = fmaf(w0, vv[j], fmaf(w1, vv[j + 1], fmaf(w2, vv[j + 2], acc[j])));
        }
        float4 o0, o1;
        o0.x = acc[0]; o0.y = acc[1]; o0.z = acc[2]; o0.w = acc[3];
        o1.x = acc[4]; o1.y = acc[5]; o1.z = acc[6]; o1.w = acc[7];
        float* drow = dst + ((long long)c << 16) + y * IMG + x8;
        *(float4*)drow = o0;
        *(float4*)(drow + 4) = o1;
    }
}

// ---------------------------------------------------------------------------
// gred: G/Sq/Sk partials from post-DW q (ch 0..191) and k (ch 0..191, separate
// buffers). Grid (128 chunks, 6 heads); lane owns 4x4 (c,d); no atomics.
// ---------------------------------------------------------------------------
__global__ __launch_bounds__(256) void gred(
    const float* __restrict__ q, const float* __restrict__ k, float* __restrict__ Gpart)
{
    __shared__ float red[4096];
    __shared__ float red2[256];
    const int t = threadIdx.x;
    const int blk = blockIdx.x, h = blockIdx.y;
    const int w = t >> 6, l = t & 63;
    const int cqd = l >> 3, dqd = l & 7;

    float acc[4][4];
    #pragma unroll
    for (int i = 0; i < 4; ++i) { acc[i][0]=0.f; acc[i][1]=0.f; acc[i][2]=0.f; acc[i][3]=0.f; }
    float sq[4] = {0.f,0.f,0.f,0.f}, sk[4] = {0.f,0.f,0.f,0.f};

    const float* qbase = q + ((long long)(h * 32 + cqd * 4) << 16);
    const float* kbase = k + ((long long)(h * 32 + dqd * 4) << 16);
    const int n0 = blk * 512 + w * 128;

    for (int it = 0; it < 32; ++it) {
        const int n = n0 + it * 4;
        float4 qa[4], kb[4];
        #pragma unroll
        for (int i = 0; i < 4; ++i) qa[i] = *(const float4*)(qbase + ((long long)i << 16) + n);
        #pragma unroll
        for (int j = 0; j < 4; ++j) kb[j] = *(const float4*)(kbase + ((long long)j << 16) + n);
        #pragma unroll
        for (int i = 0; i < 4; ++i) {
            #pragma unroll
            for (int j = 0; j < 4; ++j) {
                acc[i][j] = fmaf(qa[i].x, kb[j].x, acc[i][j]);
                acc[i][j] = fmaf(qa[i].y, kb[j].y, acc[i][j]);
                acc[i][j] = fmaf(qa[i].z, kb[j].z, acc[i][j]);
                acc[i][j] = fmaf(qa[i].w, kb[j].w, acc[i][j]);
            }
        }
        if (dqd == 0) {
            #pragma unroll
            for (int i = 0; i < 4; ++i) {
                sq[i] = fmaf(qa[i].x, qa[i].x, sq[i]);
                sq[i] = fmaf(qa[i].y, qa[i].y, sq[i]);
                sq[i] = fmaf(qa[i].z, qa[i].z, sq[i]);
                sq[i] = fmaf(qa[i].w, qa[i].w, sq[i]);
            }
        }
        if (cqd == 0) {
            #pragma unroll
            for (int j = 0; j < 4; ++j) {
                sk[j] = fmaf(kb[j].x, kb[j].x, sk[j]);
                sk[j] = fmaf(kb[j].y, kb[j].y, sk[j]);
                sk[j] = fmaf(kb[j].z, kb[j].z, sk[j]);
                sk[j] = fmaf(kb[j].w, kb[j].w, sk[j]);
            }
        }
    }

    #pragma unroll
    for (int i = 0; i < 4; ++i) {
        #pragma unroll
        for (int j = 0; j < 4; ++j)
            red[w * 1024 + (cqd * 4 + i) * 32 + dqd * 4 + j] = acc[i][j];
    }
    if (dqd == 0) {
        #pragma unroll
        for (int i = 0; i < 4; ++i) red2[w * 32 + cqd * 4 + i] = sq[i];
    }
    if (cqd == 0) {
        #pragma unroll
        for (int j = 0; j < 4; ++j) red2[128 + w * 32 + dqd * 4 + j] = sk[j];
    }
    __syncthreads();

    float* Gp = Gpart + (long long)(h * 128 + blk) * 1088;
    #pragma unroll
    for (int i = 0; i < 4; ++i) {
        int slot = t + i * 256;
        Gp[slot] = red[slot] + red[1024 + slot] + red[2048 + slot] + red[3072 + slot];
    }
    if (t < 32) {
        Gp[1024 + t] = red2[t] + red2[32 + t] + red2[64 + t] + red2[96 + t];
    } else if (t < 64) {
        int c = t - 32;
        Gp[1056 + c] = red2[128 + c] + red2[160 + c] + red2[192 + c] + red2[224 + c];
    }
}

__global__ void reduce_g(const float* __restrict__ Gpart, float* __restrict__ G,
                         float* __restrict__ Sq, float* __restrict__ Sk, int bh0)
{
    const int h = blockIdx.x, t = threadIdx.x;
    const float* Gp = Gpart + (long long)h * 128 * 1088;
    const int bh = bh0 + h;
    #pragma unroll
    for (int i = 0; i < 5; ++i) {
        int slot = t + i * 256;
        if (slot >= 1088) break;
        float s = 0.f;
        for (int tl = 0; tl < 128; ++tl) s += Gp[(long long)tl * 1088 + slot];
        if (slot < 1024)      G[(long long)bh * 1024 + slot] = s;
        else if (slot < 1056) Sq[bh * 32 + (slot - 1024)] = s;
        else                  Sk[bh * 32 + (slot - 1056)] = s;
    }
}

__global__ void attn_small(const float* __restrict__ G, const float* __restrict__ Sq,
                           const float* __restrict__ Sk, const float* __restrict__ temp,
                           const float* __restrict__ attn1, float* __restrict__ A)
{
    const int h = blockIdx.x, b = blockIdx.y, c = threadIdx.x;
    const int bh = b * 6 + h;
    const float* g = G + ((long long)bh * 32 + c) * 32;
    const float nq = fmaxf(sqrtf(Sq[bh * 32 + c]), 1e-12f);
    const float T  = temp[h];
    const float a1 = attn1[0];

    float a[32];
    #pragma unroll
    for (int d = 0; d < 32; ++d) {
        float nk = fmaxf(sqrtf(Sk[bh * 32 + d]), 1e-12f);
        a[d] = g[d] / (nq * nk) * T;
    }
    unsigned mask = 0u;
    float m = 0.f, kth = 0.f;
    for (int it = 0; it < 16; ++it) {
        float best = -3.4e38f; int bi = 0;
        #pragma unroll
        for (int d = 0; d < 32; ++d) {
            bool avail = ((mask >> d) & 1u) == 0u;
            if (avail && a[d] > best) { best = a[d]; bi = d; }
        }
        mask |= (1u << bi);
        if (it == 0) m = best;
        kth = best;
    }
    float denom = 0.f;
    #pragma unroll
    for (int d = 0; d < 32; ++d) if (a[d] >= kth) denom += expf(a[d] - m);
    const float inv = a1 / denom;
    float* Ar = A + ((long long)bh * 32 + c) * 32;
    #pragma unroll
    for (int d = 0; d < 32; ++d) Ar[d] = (a[d] >= kth) ? expf(a[d] - m) * inv : 0.f;
}

__global__ void make_m(const float* __restrict__ proj_w, const float* __restrict__ A,
                       float* __restrict__ M)
{
    const int o = blockIdx.x, b = blockIdx.y, j = threadIdx.x;
    const int hd = j >> 5, d = j & 31;
    const float* pw = proj_w + o * 192 + hd * 32;
    const float* Ah = A + ((long long)(b * 6 + hd) * 32) * 32 + d;
    float s = 0.f;
    #pragma unroll
    for (int cq = 0; cq < 32; ++cq) s = fmaf(pw[cq], Ah[cq * 32], s);
    M[((long long)(b * 192 + o)) * 192 + j] = s;
}

// ---------------------------------------------------------------------------
extern "C" void kernel_launch(void* const* d_in, const int* in_sizes, int n_in,
                              void* d_out, int out_size, void* d_ws, size_t ws_size,
                              hipStream_t stream)
{
    const float* x      = (const float*)d_in[0];
    const float* qkv_w  = (const float*)d_in[1];
    const float* dww    = (const float*)d_in[2];
    const float* proj_w = (const float*)d_in[3];
    const float* temp   = (const float*)d_in[4];
    const float* attn1  = (const float*)d_in[5];
    float* out = (float*)d_out;
    float* wsf = (float*)d_ws;

    // ws layout (floats) -- total = proven-safe 101,059,584 bytes
    float* G   = wsf;                 // 12,288
    float* Sq  = G + 12288;           // 384
    float* Sk  = Sq + 384;            // 384
    float* A   = Sk + 384;            // 12,288
    float* Mm  = A + 12288;           // 73,728
    float* buf = Mm + 73728;          // 96 MiB

    const long long PL = 12582912LL;  // floats per 48 MiB region
    float* W1 = buf;                  // ws halves
    float* W2 = buf + PL;
    float* R1 = out;                  // d_out halves (= batch regions)
    float* R2 = out + PL;

    // Phase S: attention statistics per batch.
    //  Xt(x) -> R1 ; K1qk -> buf (q@W1, k@W2) ; dw-q: W1->R2 ; dw-k: W2->W1 ;
    //  gred(R2, W1) -> Gpart@W2 ; reduce_g.
    for (int b = 0; b < 2; ++b) {
        const float* xb = x + (long long)b * PL;
        ushort* XtH = (ushort*)R1;
        ushort* XtL = (ushort*)R1 + PL;
        transp_conv<<<dim3(1024, 6), 256, 0, stream>>>(xb, XtH, XtL);
        gemm_mfma<<<dim3(256, 6), 256, 0, stream>>>(qkv_w, 0, XtH, XtL, buf);
        dwconv8<<<dim3(32, 48), 256, 0, stream>>>(W1, dww, R2);            // q post
        dwconv8<<<dim3(32, 48), 256, 0, stream>>>(W2, dww + 192 * 9, W1);  // k post
        gred<<<dim3(128, 6), 256, 0, stream>>>(R2, W1, W2);
        reduce_g<<<dim3(6, 1), 256, 0, stream>>>(W2, G, Sq, Sk, b * 6);
    }

    // Phase B: tiny attention matrices + fused projection matrix
    attn_small<<<dim3(6, 2), 32, 0, stream>>>(G, Sq, Sk, temp, attn1, A);
    make_m<<<dim3(192, 2), 192, 0, stream>>>(proj_w, A, Mm);

    // Phase V: v path per batch: Xt(x)->W1 ; K1v -> W2 ; dwconv-v -> d_out[b]
    for (int b = 0; b < 2; ++b) {
        const float* xb = x + (long long)b * PL;
        ushort* XtH = (ushort*)W1;
        ushort* XtL = (ushort*)W1 + PL;
        transp_conv<<<dim3(1024, 6), 256, 0, stream>>>(xb, XtH, XtL);
        gemm_mfma<<<dim3(256, 3), 256, 0, stream>>>(qkv_w, 384, XtH, XtL, W2);
        dwconv8<<<dim3(32, 48), 256, 0, stream>>>(W2, dww + 384 * 9, out + (long long)b * PL);
    }

    // Phase K4: per batch: vT(v-post)->W1 ; out[b] = M_b @ v (reads ws, writes d_out)
    for (int b = 0; b < 2; ++b) {
        float* outb = out + (long long)b * PL;
        ushort* vTH = (ushort*)W1;
        ushort* vTL = (ushort*)W1 + PL;
        transp_conv<<<dim3(1024, 6), 256, 0, stream>>>(outb, vTH, vTL);
        gemm_mfma<<<dim3(256, 3), 256, 0, stream>>>(Mm + (long long)b * 36864, 0, vTH, vTL, outb);
    }
}

// Round 9
// 712.566 us; speedup vs baseline: 3.3623x; 1.0525x over previous
//
#include <hip/hip_runtime.h>
#include <math.h>

#define N_SP 65536   // h*w
#define IMG  256

typedef __attribute__((ext_vector_type(8))) short s16x8;
typedef __attribute__((ext_vector_type(4))) float f32x4;

// RNE fp32->bf16 (bit version, deterministic) and back
__device__ inline ushort f2bf(float f) {
    uint u = __float_as_uint(f);
    return (ushort)((u + 0x7FFFu + ((u >> 16) & 1u)) >> 16);
}
__device__ inline float bf2f(ushort h) { return __uint_as_float(((uint)h) << 16); }
__device__ inline uint pk2(ushort a, ushort b) { return (uint)a | ((uint)b << 16); }

// ---------------------------------------------------------------------------
// transp_conv: src fp32 [192][65536] -> hi/lo bf16 planes TRANSPOSED [65536][192].
// Tile 32c x 64n via LDS. Used for x (per batch) and post-DW v.
// ---------------------------------------------------------------------------
__global__ __launch_bounds__(256) void transp_conv(
    const float* __restrict__ src, ushort* __restrict__ hi, ushort* __restrict__ lo)
{
    __shared__ float T[32][65];
    const int t = threadIdx.x;
    const int n0 = blockIdx.x * 64, c0 = blockIdx.y * 32;
    {
        const int cb = t >> 6, n = t & 63;
        #pragma unroll
        for (int i = 0; i < 8; ++i) {
            const int c = cb + i * 4;
            T[c][n] = src[(long long)(c0 + c) * N_SP + n0 + n];
        }
    }
    __syncthreads();
    const int n = t >> 2, cq = (t & 3) * 8;
    float v[8];
    #pragma unroll
    for (int j = 0; j < 8; ++j) v[j] = T[cq + j][n];
    ushort h[8], l[8];
    #pragma unroll
    for (int j = 0; j < 8; ++j) { h[j] = f2bf(v[j]); l[j] = f2bf(v[j] - bf2f(h[j])); }
    uint4 H, L;
    H.x = pk2(h[0], h[1]); H.y = pk2(h[2], h[3]); H.z = pk2(h[4], h[5]); H.w = pk2(h[6], h[7]);
    L.x = pk2(l[0], l[1]); L.y = pk2(l[2], l[3]); L.z = pk2(l[4], l[5]); L.w = pk2(l[6], l[7]);
    const long long o = (long long)(n0 + n) * 192 + c0 + cq;
    *(uint4*)(hi + o) = H;
    *(uint4*)(lo + o) = L;
}

// ---------------------------------------------------------------------------
// gemm_mfma: C[m][n] = sum_k Wf[wrow0+m][k] * X[k][n], K=192, split-bf16:
// C = Whi*Xhi + Whi*Xlo + Wlo*Xhi (lo*lo dropped, ~1e-5 rel).
// A (W) converted hi/lo in-kernel during LDS staging; B from pre-transposed
// planes [n][192]. Tile M=64 x N=256, 4 waves, K-step 32.
// Round-8 lesson: Xs stride 32 ushorts (64B rows) made B-frag ds_read_b128
// an 8-way bank conflict (2.95M/dispatch); stride 40 (80B, 16B-aligned)
// spreads start banks over 8 -> 2-way (free). Ws already stride 40.
// C/D (m89): col=lane&15, row=(lane>>4)*4+j.
// ---------------------------------------------------------------------------
__global__ __launch_bounds__(256) void gemm_mfma(
    const float* __restrict__ Wf, int wrow0,
    const ushort* __restrict__ XtHi, const ushort* __restrict__ XtLo,
    float* __restrict__ C)
{
    __shared__ ushort WsH[64][40], WsL[64][40];
    __shared__ ushort XsH[256][40], XsL[256][40];
    const int t  = threadIdx.x;
    const int wv = t >> 6, l = t & 63;
    const int lc = l & 15, lg = l >> 4;
    const int m0 = blockIdx.y * 64;
    const long long n0 = (long long)blockIdx.x * 256;

    f32x4 acc[4][4];
    #pragma unroll
    for (int i = 0; i < 4; ++i)
        #pragma unroll
        for (int j = 0; j < 4; ++j) acc[i][j] = (f32x4)(0.f);

    const int ar = t >> 2, ak = (t & 3) * 8;

    for (int kc = 0; kc < 192; kc += 32) {
        {
            const float* wp = Wf + (long long)(wrow0 + m0 + ar) * 192 + kc + ak;
            const float4 a0 = *(const float4*)wp;
            const float4 a1 = *(const float4*)(wp + 4);
            const float v[8] = {a0.x, a0.y, a0.z, a0.w, a1.x, a1.y, a1.z, a1.w};
            ushort h[8], lo_[8];
            #pragma unroll
            for (int j = 0; j < 8; ++j) { h[j] = f2bf(v[j]); lo_[j] = f2bf(v[j] - bf2f(h[j])); }
            uint4 H, L;
            H.x = pk2(h[0],h[1]); H.y = pk2(h[2],h[3]); H.z = pk2(h[4],h[5]); H.w = pk2(h[6],h[7]);
            L.x = pk2(lo_[0],lo_[1]); L.y = pk2(lo_[2],lo_[3]); L.z = pk2(lo_[4],lo_[5]); L.w = pk2(lo_[6],lo_[7]);
            *(uint4*)&WsH[ar][ak] = H;
            *(uint4*)&WsL[ar][ak] = L;
        }
        #pragma unroll
        for (int i = 0; i < 4; ++i) {
            const int chunk = t + i * 256;
            const int r = chunk >> 2, ko = (chunk & 3) * 8;
            const long long g = (n0 + r) * 192 + kc + ko;
            *(uint4*)&XsH[r][ko] = *(const uint4*)(XtHi + g);
            *(uint4*)&XsL[r][ko] = *(const uint4*)(XtLo + g);
        }
        __syncthreads();

        s16x8 ah[4], al[4];
        #pragma unroll
        for (int mf = 0; mf < 4; ++mf) {
            ah[mf] = *(const s16x8*)&WsH[mf * 16 + lc][lg * 8];
            al[mf] = *(const s16x8*)&WsL[mf * 16 + lc][lg * 8];
        }
        #pragma unroll
        for (int nf = 0; nf < 4; ++nf) {
            const int nr = wv * 64 + nf * 16 + lc;
            const s16x8 bh = *(const s16x8*)&XsH[nr][lg * 8];
            const s16x8 bl = *(const s16x8*)&XsL[nr][lg * 8];
            #pragma unroll
            for (int mf = 0; mf < 4; ++mf) {
                acc[mf][nf] = __builtin_amdgcn_mfma_f32_16x16x32_bf16(ah[mf], bh, acc[mf][nf], 0, 0, 0);
                acc[mf][nf] = __builtin_amdgcn_mfma_f32_16x16x32_bf16(ah[mf], bl, acc[mf][nf], 0, 0, 0);
                acc[mf][nf] = __builtin_amdgcn_mfma_f32_16x16x32_bf16(al[mf], bh, acc[mf][nf], 0, 0, 0);
            }
        }
        __syncthreads();
    }

    #pragma unroll
    for (int mf = 0; mf < 4; ++mf)
        #pragma unroll
        for (int nf = 0; nf < 4; ++nf) {
            const long long nn = n0 + wv * 64 + nf * 16 + lc;
            #pragma unroll
            for (int j = 0; j < 4; ++j)
                C[(long long)(m0 + mf * 16 + lg * 4 + j) * N_SP + nn] = acc[mf][nf][j];
        }
}

// ---------------------------------------------------------------------------
// dwconv8: depthwise 3x3, register-shift, 8 px x 4 channels per thread.
// 56 VMEM per 32 px via float4 loads; halo via clamped loads + zeroed weights.
// ---------------------------------------------------------------------------
__global__ __launch_bounds__(256) void dwconv8(
    const float* __restrict__ src, const float* __restrict__ dww, float* __restrict__ dst)
{
    const int t = threadIdx.x;
    const int s = blockIdx.x * 256 + t;
    const int y = s >> 5;
    const int x8 = (s & 31) * 8;
    const int cg = blockIdx.y;

    const int xl = (x8 == 0) ? 0 : x8 - 4;
    const int xr = (x8 == 248) ? 248 : x8 + 8;

    #pragma unroll
    for (int i = 0; i < 4; ++i) {
        const int c = cg * 4 + i;
        const float* base = src + ((long long)c << 16);
        const float* wp = dww + c * 9;
        float acc[8];
        #pragma unroll
        for (int j = 0; j < 8; ++j) acc[j] = 0.f;
        #pragma unroll
        for (int dy = 0; dy < 3; ++dy) {
            const int yy = y + dy - 1;
            const bool vld = (yy >= 0 && yy < IMG);
            const float* row = base + (vld ? yy : y) * IMG;
            const float w0 = vld ? wp[dy * 3 + 0] : 0.f;
            const float w1 = vld ? wp[dy * 3 + 1] : 0.f;
            const float w2 = vld ? wp[dy * 3 + 2] : 0.f;
            const float4 Lq = *(const float4*)(row + xl);
            const float4 M0 = *(const float4*)(row + x8);
            const float4 M1 = *(const float4*)(row + x8 + 4);
            const float4 Rq = *(const float4*)(row + xr);
            float vv[10];
            vv[0] = (x8 == 0) ? 0.f : Lq.w;
            vv[1] = M0.x; vv[2] = M0.y; vv[3] = M0.z; vv[4] = M0.w;
            vv[5] = M1.x; vv[6] = M1.y; vv[7] = M1.z; vv[8] = M1.w;
            vv[9] = (x8 == 248) ? 0.f : Rq.x;
            #pragma unroll
            for (int j = 0; j < 8; ++j)
                acc[j] = fmaf(w0, vv[j], fmaf(w1, vv[j + 1], fmaf(w2, vv[j + 2], acc[j])));
        }
        float4 o0, o1;
        o0.x = acc[0]; o0.y = acc[1]; o0.z = acc[2]; o0.w = acc[3];
        o1.x = acc[4]; o1.y = acc[5]; o1.z = acc[6]; o1.w = acc[7];
        float* drow = dst + ((long long)c << 16) + y * IMG + x8;
        *(float4*)drow = o0;
        *(float4*)(drow + 4) = o1;
    }
}

// ---------------------------------------------------------------------------
// gred: G/Sq/Sk partials from post-DW q,k (separate buffers, 192 ch each).
// Grid (128 chunks, 6 heads); lane owns 4x4 (c,d); no atomics.
// ---------------------------------------------------------------------------
__global__ __launch_bounds__(256) void gred(
    const float* __restrict__ q, const float* __restrict__ k, float* __restrict__ Gpart)
{
    __shared__ float red[4096];
    __shared__ float red2[256];
    const int t = threadIdx.x;
    const int blk = blockIdx.x, h = blockIdx.y;
    const int w = t >> 6, l = t & 63;
    const int cqd = l >> 3, dqd = l & 7;

    float acc[4][4];
    #pragma unroll
    for (int i = 0; i < 4; ++i) { acc[i][0]=0.f; acc[i][1]=0.f; acc[i][2]=0.f; acc[i][3]=0.f; }
    float sq[4] = {0.f,0.f,0.f,0.f}, sk[4] = {0.f,0.f,0.f,0.f};

    const float* qbase = q + ((long long)(h * 32 + cqd * 4) << 16);
    const float* kbase = k + ((long long)(h * 32 + dqd * 4) << 16);
    const int n0 = blk * 512 + w * 128;

    for (int it = 0; it < 32; ++it) {
        const int n = n0 + it * 4;
        float4 qa[4], kb[4];
        #pragma unroll
        for (int i = 0; i < 4; ++i) qa[i] = *(const float4*)(qbase + ((long long)i << 16) + n);
        #pragma unroll
        for (int j = 0; j < 4; ++j) kb[j] = *(const float4*)(kbase + ((long long)j << 16) + n);
        #pragma unroll
        for (int i = 0; i < 4; ++i) {
            #pragma unroll
            for (int j = 0; j < 4; ++j) {
                acc[i][j] = fmaf(qa[i].x, kb[j].x, acc[i][j]);
                acc[i][j] = fmaf(qa[i].y, kb[j].y, acc[i][j]);
                acc[i][j] = fmaf(qa[i].z, kb[j].z, acc[i][j]);
                acc[i][j] = fmaf(qa[i].w, kb[j].w, acc[i][j]);
            }
        }
        if (dqd == 0) {
            #pragma unroll
            for (int i = 0; i < 4; ++i) {
                sq[i] = fmaf(qa[i].x, qa[i].x, sq[i]);
                sq[i] = fmaf(qa[i].y, qa[i].y, sq[i]);
                sq[i] = fmaf(qa[i].z, qa[i].z, sq[i]);
                sq[i] = fmaf(qa[i].w, qa[i].w, sq[i]);
            }
        }
        if (cqd == 0) {
            #pragma unroll
            for (int j = 0; j < 4; ++j) {
                sk[j] = fmaf(kb[j].x, kb[j].x, sk[j]);
                sk[j] = fmaf(kb[j].y, kb[j].y, sk[j]);
                sk[j] = fmaf(kb[j].z, kb[j].z, sk[j]);
                sk[j] = fmaf(kb[j].w, kb[j].w, sk[j]);
            }
        }
    }

    #pragma unroll
    for (int i = 0; i < 4; ++i) {
        #pragma unroll
        for (int j = 0; j < 4; ++j)
            red[w * 1024 + (cqd * 4 + i) * 32 + dqd * 4 + j] = acc[i][j];
    }
    if (dqd == 0) {
        #pragma unroll
        for (int i = 0; i < 4; ++i) red2[w * 32 + cqd * 4 + i] = sq[i];
    }
    if (cqd == 0) {
        #pragma unroll
        for (int j = 0; j < 4; ++j) red2[128 + w * 32 + dqd * 4 + j] = sk[j];
    }
    __syncthreads();

    float* Gp = Gpart + (long long)(h * 128 + blk) * 1088;
    #pragma unroll
    for (int i = 0; i < 4; ++i) {
        int slot = t + i * 256;
        Gp[slot] = red[slot] + red[1024 + slot] + red[2048 + slot] + red[3072 + slot];
    }
    if (t < 32) {
        Gp[1024 + t] = red2[t] + red2[32 + t] + red2[64 + t] + red2[96 + t];
    } else if (t < 64) {
        int c = t - 32;
        Gp[1056 + c] = red2[128 + c] + red2[160 + c] + red2[192 + c] + red2[224 + c];
    }
}

__global__ void reduce_g(const float* __restrict__ Gpart, float* __restrict__ G,
                         float* __restrict__ Sq, float* __restrict__ Sk, int bh0)
{
    const int h = blockIdx.x, t = threadIdx.x;
    const float* Gp = Gpart + (long long)h * 128 * 1088;
    const int bh = bh0 + h;
    #pragma unroll
    for (int i = 0; i < 5; ++i) {
        int slot = t + i * 256;
        if (slot >= 1088) break;
        float s = 0.f;
        for (int tl = 0; tl < 128; ++tl) s += Gp[(long long)tl * 1088 + slot];
        if (slot < 1024)      G[(long long)bh * 1024 + slot] = s;
        else if (slot < 1056) Sq[bh * 32 + (slot - 1024)] = s;
        else                  Sk[bh * 32 + (slot - 1056)] = s;
    }
}

__global__ void attn_small(const float* __restrict__ G, const float* __restrict__ Sq,
                           const float* __restrict__ Sk, const float* __restrict__ temp,
                           const float* __restrict__ attn1, float* __restrict__ A)
{
    const int h = blockIdx.x, b = blockIdx.y, c = threadIdx.x;
    const int bh = b * 6 + h;
    const float* g = G + ((long long)bh * 32 + c) * 32;
    const float nq = fmaxf(sqrtf(Sq[bh * 32 + c]), 1e-12f);
    const float T  = temp[h];
    const float a1 = attn1[0];

    float a[32];
    #pragma unroll
    for (int d = 0; d < 32; ++d) {
        float nk = fmaxf(sqrtf(Sk[bh * 32 + d]), 1e-12f);
        a[d] = g[d] / (nq * nk) * T;
    }
    unsigned mask = 0u;
    float m = 0.f, kth = 0.f;
    for (int it = 0; it < 16; ++it) {
        float best = -3.4e38f; int bi = 0;
        #pragma unroll
        for (int d = 0; d < 32; ++d) {
            bool avail = ((mask >> d) & 1u) == 0u;
            if (avail && a[d] > best) { best = a[d]; bi = d; }
        }
        mask |= (1u << bi);
        if (it == 0) m = best;
        kth = best;
    }
    float denom = 0.f;
    #pragma unroll
    for (int d = 0; d < 32; ++d) if (a[d] >= kth) denom += expf(a[d] - m);
    const float inv = a1 / denom;
    float* Ar = A + ((long long)bh * 32 + c) * 32;
    #pragma unroll
    for (int d = 0; d < 32; ++d) Ar[d] = (a[d] >= kth) ? expf(a[d] - m) * inv : 0.f;
}

__global__ void make_m(const float* __restrict__ proj_w, const float* __restrict__ A,
                       float* __restrict__ M)
{
    const int o = blockIdx.x, b = blockIdx.y, j = threadIdx.x;
    const int hd = j >> 5, d = j & 31;
    const float* pw = proj_w + o * 192 + hd * 32;
    const float* Ah = A + ((long long)(b * 6 + hd) * 32) * 32 + d;
    float s = 0.f;
    #pragma unroll
    for (int cq = 0; cq < 32; ++cq) s = fmaf(pw[cq], Ah[cq * 32], s);
    M[((long long)(b * 192 + o)) * 192 + j] = s;
}

// ---------------------------------------------------------------------------
extern "C" void kernel_launch(void* const* d_in, const int* in_sizes, int n_in,
                              void* d_out, int out_size, void* d_ws, size_t ws_size,
                              hipStream_t stream)
{
    const float* x      = (const float*)d_in[0];
    const float* qkv_w  = (const float*)d_in[1];
    const float* dww    = (const float*)d_in[2];
    const float* proj_w = (const float*)d_in[3];
    const float* temp   = (const float*)d_in[4];
    const float* attn1  = (const float*)d_in[5];
    float* out = (float*)d_out;
    float* wsf = (float*)d_ws;

    // ws layout (floats) -- total = proven-safe 101,059,584 bytes
    float* G   = wsf;                 // 12,288
    float* Sq  = G + 12288;           // 384
    float* Sk  = Sq + 384;            // 384
    float* A   = Sk + 384;            // 12,288
    float* Mm  = A + 12288;           // 73,728
    float* buf = Mm + 73728;          // 96 MiB

    const long long PL = 12582912LL;  // floats per 48 MiB region (= ushorts per 24 MiB plane pair)
    float* W1 = buf;
    float* W2 = buf + PL;
    float* R1 = out;                  // batch-0 out region
    float* R2 = out + PL;             // batch-1 out region

    ushort* R1H = (ushort*)R1; ushort* R1L = R1H + PL;
    ushort* W2H = (ushort*)W2; ushort* W2L = W2H + PL;

    // ---- Phase S, b=0: Xt(x0)@R1 ; qk gemm -> q@W1,k@W2 ; dw ; gred ; reduce
    transp_conv<<<dim3(1024, 6), 256, 0, stream>>>(x, R1H, R1L);
    gemm_mfma<<<dim3(256, 6), 256, 0, stream>>>(qkv_w, 0, R1H, R1L, buf);
    dwconv8<<<dim3(32, 48), 256, 0, stream>>>(W1, dww, R2);            // qpost
    dwconv8<<<dim3(32, 48), 256, 0, stream>>>(W2, dww + 192 * 9, W1);  // kpost
    gred<<<dim3(128, 6), 256, 0, stream>>>(R2, W1, W2);
    reduce_g<<<dim3(6, 1), 256, 0, stream>>>(W2, G, Sq, Sk, 0);

    // ---- Phase S, b=1: Xt(x1)@R1 stays ALIVE for the v-path (round-8 reorder)
    transp_conv<<<dim3(1024, 6), 256, 0, stream>>>(x + PL, R1H, R1L);
    gemm_mfma<<<dim3(256, 6), 256, 0, stream>>>(qkv_w, 0, R1H, R1L, buf);
    dwconv8<<<dim3(32, 48), 256, 0, stream>>>(W1, dww, R2);
    dwconv8<<<dim3(32, 48), 256, 0, stream>>>(W2, dww + 192 * 9, W1);
    gred<<<dim3(128, 6), 256, 0, stream>>>(R2, W1, W2);
    reduce_g<<<dim3(6, 1), 256, 0, stream>>>(W2, G, Sq, Sk, 6);

    // ---- Phase B: tiny attention matrices + fused projection matrices
    attn_small<<<dim3(6, 2), 32, 0, stream>>>(G, Sq, Sk, temp, attn1, A);
    make_m<<<dim3(192, 2), 192, 0, stream>>>(proj_w, A, Mm);

    // ---- V+K4, b=1 (reuses Xt(x1)@R1): K1v->W2 ; dwv->W1 ; vT->W2 ; K4->R2
    gemm_mfma<<<dim3(256, 3), 256, 0, stream>>>(qkv_w, 384, R1H, R1L, W2);
    dwconv8<<<dim3(32, 48), 256, 0, stream>>>(W2, dww + 384 * 9, W1);
    transp_conv<<<dim3(1024, 6), 256, 0, stream>>>(W1, W2H, W2L);
    gemm_mfma<<<dim3(256, 3), 256, 0, stream>>>(Mm + 36864, 0, W2H, W2L, R2);

    // ---- V+K4, b=0: Xt(x0)@R1 ; K1v->W2 ; dwv->W1 ; vT->W2 ; K4->R1 (final)
    transp_conv<<<dim3(1024, 6), 256, 0, stream>>>(x, R1H, R1L);
    gemm_mfma<<<dim3(256, 3), 256, 0, stream>>>(qkv_w, 384, R1H, R1L, W2);
    dwconv8<<<dim3(32, 48), 256, 0, stream>>>(W2, dww + 384 * 9, W1);
    transp_conv<<<dim3(1024, 6), 256, 0, stream>>>(W1, W2H, W2L);
    gemm_mfma<<<dim3(256, 3), 256, 0, stream>>>(Mm, 0, W2H, W2L, R1);
}